// Round 14
// baseline (832.103 us; speedup 1.0000x reference)
//
#include <hip/hip_runtime.h>
#include <math.h>

#define BQ 4
#define SQ 2048
#define DQ 512
#define YQ 8922
#define TQ 32
#define EQ 100
#define EP 128      // E padded for MFMA K-steps
#define KQ 9
#define LD 128      // LDS leading dim (bf16) = 256B rows, 4-bit XOR swizzle
#define YPAD 8960

typedef float f32x4 __attribute__((ext_vector_type(4)));
typedef short s16x8 __attribute__((ext_vector_type(8)));

static __device__ __forceinline__ f32x4 mfma16(s16x8 a, s16x8 b, f32x4 c) {
  return __builtin_amdgcn_mfma_f32_16x16x32_bf16(a, b, c, 0, 0, 0);
}

static __device__ __forceinline__ ushort f2bf(float f) {
  union { float f; unsigned u; } v; v.f = f;
  unsigned r = (v.u + 0x7FFFu + ((v.u >> 16) & 1u)) >> 16;
  return (ushort)r;
}

static __device__ __forceinline__ float bf2f(ushort h) {
  union { unsigned u; float f; } v; v.u = ((unsigned)h) << 16; return v.f;
}

// unaligned (4B) 16-byte load/store
static __device__ __forceinline__ f32x4 ld4u(const float* p) {
  f32x4 v; __builtin_memcpy(&v, p, 16); return v;
}
static __device__ __forceinline__ void st4u(float* p, f32x4 v) {
  __builtin_memcpy(p, &v, 16);
}

// 4-bit XOR swizzle for 128-elem (256B) rows: 16 chunks (R3-proven)
static __device__ __forceinline__ int swz_chunk(int row, int chunk) {
  return chunk ^ (row & 15);
}
// 3-bit XOR swizzle for 64-elem (128B) rows: 8 chunks (pv2-proven)
static __device__ __forceinline__ int swz3(int row, int chunk) {
  return chunk ^ (row & 7);
}
// 2-bit XOR swizzle for 32-elem (64B) rows: 4 chunks (R14 conv sB)
static __device__ __forceinline__ int swz2(int row, int chunk) {
  return chunk ^ (row & 3);
}

// ---- prep: x -> bf16 [B][S][D] and transposed [B][D][S]; vectorized --------
__global__ void k_prep_x(const float* __restrict__ x, ushort* __restrict__ xb,
                         ushort* __restrict__ xT) {
  __shared__ ushort sm[64][66];
  int b = blockIdx.z;
  int s0 = blockIdx.x * 64;
  int d0 = blockIdx.y * 64;
  int tid = threadIdx.x;
  int sr = tid >> 4;
  int c4 = (tid & 15) * 4;
  #pragma unroll
  for (int it = 0; it < 4; ++it) {
    int s = sr + it * 16;
    f32x4 v = *(const f32x4*)(x + ((size_t)b * SQ + s0 + s) * DQ + d0 + c4);
    ushort4 h = make_ushort4(f2bf(v.x), f2bf(v.y), f2bf(v.z), f2bf(v.w));
    *(ushort4*)(xb + ((size_t)b * SQ + s0 + s) * DQ + d0 + c4) = h;
    sm[s][c4] = h.x; sm[s][c4 + 1] = h.y; sm[s][c4 + 2] = h.z; sm[s][c4 + 3] = h.w;
  }
  __syncthreads();
  #pragma unroll
  for (int it = 0; it < 4; ++it) {
    int d = sr + it * 16;
    ushort4 h;
    h.x = sm[c4][d]; h.y = sm[c4 + 1][d]; h.z = sm[c4 + 2][d]; h.w = sm[c4 + 3][d];
    *(ushort4*)(xT + ((size_t)b * DQ + d0 + d) * SQ + s0 + c4) = h;
  }
}

// ---------------- pack conv_w [D][E][K] -> Wp bf16 [K][D][EP] (e>=100 -> 0) --
__global__ void k_pack_w(const float* __restrict__ cw, ushort* __restrict__ Wp) {
  int i = blockIdx.x * 256 + threadIdx.x;
  if (i >= KQ * DQ * EP) return;
  int e = i & (EP - 1);
  int d = (i >> 7) & (DQ - 1);
  int kk = i >> 16;
  float v = (e < EQ) ? cw[((size_t)d * EQ + e) * KQ + kk] : 0.f;
  Wp[i] = f2bf(v);
}

// ---- conv + maxpool + tanh + scale -> U bf16 [YQ][D] -----------------------
// R14: 40 KB LDS (sB 8KB = 128d x 32e, one e-chunk per step, 36 steps) ->
// 4 blocks/CU (R13 was 3 @ 48KB). m114 cross-block overlap hides barriers.
__launch_bounds__(256, 4)
__global__ void k_conv(const int* __restrict__ c2t, const float* __restrict__ embed,
                       const ushort* __restrict__ Wp, const float* __restrict__ cb,
                       ushort* __restrict__ U) {
  __shared__ ushort sA[4 * TQ * LD];   // 32 KB: 4 labels x 32 t x 128 e
  __shared__ ushort sB[128 * 32];      //  8 KB: 128 d x 32 e (one step)
  const f32x4 fz4 = {0.f, 0.f, 0.f, 0.f};
  const s16x8 sz8 = {0, 0, 0, 0, 0, 0, 0, 0};
  int tid = threadIdx.x;
  int d0 = blockIdx.x * 128;
  int y0 = blockIdx.y * 4;
  int lane = tid & 63, wave = tid >> 6;
  int wm = wave & 1, wn = wave >> 1;
  int lr = lane & 15, lg = lane >> 4;

  // stage all title embeddings for 4 labels: [4*32] rows x [LD] bf16, swizzled
  {
    int row = tid >> 1;
    int half = tid & 1;
    int yl = row >> 5, t = row & 31;
    int y = y0 + yl;
    const float* src = 0;
    if (y < YQ) src = embed + (size_t)c2t[y * TQ + t] * EQ + half * 64;
    #pragma unroll
    for (int j = 0; j < 16; ++j) {
      int col = half * 64 + j * 4;
      f32x4 v = fz4;
      if (src != 0 && col + 4 <= EQ) v = *(const f32x4*)(src + j * 4);
      ushort4 h = make_ushort4(f2bf(v.x), f2bf(v.y), f2bf(v.z), f2bf(v.w));
      int pc = swz_chunk(row, col >> 3);
      *(ushort4*)&sA[row * LD + pc * 8 + (col & 7)] = h;
    }
  }

  // prologue: stage sB for step 0 (kk=0, ee=0) via registers
  s16x8 breg[2];
  {
    const ushort* src = Wp + (size_t)d0 * EP;
    #pragma unroll
    for (int p = 0; p < 2; ++p) {
      int gi = tid + p * 256, r = gi >> 2, c = gi & 3;
      breg[p] = *(const s16x8*)(src + (size_t)r * EP + c * 8);
    }
    #pragma unroll
    for (int p = 0; p < 2; ++p) {
      int gi = tid + p * 256, r = gi >> 2, c = gi & 3;
      *(s16x8*)&sB[r * 32 + swz2(r, c) * 8] = breg[p];
    }
  }
  __syncthreads();

  f32x4 acc[4][4];
  #pragma unroll
  for (int i = 0; i < 4; ++i)
    #pragma unroll
    for (int j = 0; j < 4; ++j) acc[i][j] = fz4;

  for (int step = 0; step < 4 * KQ; ++step) {
    int kk = step >> 2, ee = step & 3;
    // T14: issue next-step weight loads into regs BEFORE compute
    if (step + 1 < 4 * KQ) {
      int kk2 = (step + 1) >> 2, ee2 = (step + 1) & 3;
      const ushort* src = Wp + ((size_t)kk2 * DQ + d0) * EP + ee2 * 32;
      #pragma unroll
      for (int p = 0; p < 2; ++p) {
        int gi = tid + p * 256, r = gi >> 2, c = gi & 3;
        breg[p] = *(const s16x8*)(src + (size_t)r * EP + c * 8);
      }
    }
    {
      s16x8 af[4], bfr[4];
      #pragma unroll
      for (int i = 0; i < 4; ++i) {
        int rowm = wm * 64 + i * 16 + lr;
        int yl = rowm >> 5;
        int ts = (rowm & 31) + kk - 4;   // shifted time index
        s16x8 a = sz8;
        if ((unsigned)ts < (unsigned)TQ) {
          int row = yl * TQ + ts;
          a = *(const s16x8*)&sA[row * LD + swz_chunk(row, ee * 4 + lg) * 8];
        }
        af[i] = a;
      }
      #pragma unroll
      for (int i = 0; i < 4; ++i) {
        int row = wn * 64 + i * 16 + lr;
        bfr[i] = *(const s16x8*)&sB[row * 32 + swz2(row, lg) * 8];
      }
      #pragma unroll
      for (int i = 0; i < 4; ++i)
        #pragma unroll
        for (int j = 0; j < 4; ++j)
          acc[i][j] = mfma16(af[i], bfr[j], acc[i][j]);
    }
    __syncthreads();           // all waves done reading sB for this step
    if (step + 1 < 4 * KQ) {
      #pragma unroll
      for (int p = 0; p < 2; ++p) {
        int gi = tid + p * 256, r = gi >> 2, c = gi & 3;
        *(s16x8*)&sB[r * 32 + swz2(r, c) * 8] = breg[p];
      }
      __syncthreads();         // sB(step+1) visible
    }
  }

  // in-register epilogue: maxpool over t via in-lane fmax + shfl, tanh, scale
  const float scl = 0.04419417382415922f;   // 1/sqrt(D)
  #pragma unroll
  for (int L2 = 0; L2 < 2; ++L2) {
    int y = y0 + wm * 2 + L2;
    #pragma unroll
    for (int j = 0; j < 4; ++j) {
      float mx = -3.0e38f;
      #pragma unroll
      for (int ii = 0; ii < 2; ++ii)
        #pragma unroll
        for (int q = 0; q < 4; ++q)
          mx = fmaxf(mx, acc[L2 * 2 + ii][j][q]);
      mx = fmaxf(mx, __shfl_xor(mx, 16));
      mx = fmaxf(mx, __shfl_xor(mx, 32));
      if (lane < 16 && y < YQ) {
        int col = d0 + wn * 64 + j * 16 + lane;
        U[(size_t)y * DQ + col] = f2bf(tanhf(mx + cb[col]) * scl);
      }
    }
  }
}

// ---- scores: U . xb^T -> P=exp(S-Mloc) bf16 (fused) or raw S f32 (fallback)
//      + per-(row,64col) {max,sumexp} partials --------------------------------
__launch_bounds__(256, 2)
__global__ void k_scores(const ushort* __restrict__ U, const ushort* __restrict__ xb,
                         ushort* __restrict__ Pb, float* __restrict__ sc,
                         float* __restrict__ part) {
  __shared__ ushort sA[128 * LD];
  __shared__ ushort sB[128 * LD];
  const f32x4 fz4 = {0.f, 0.f, 0.f, 0.f};
  int tid = threadIdx.x;
  int s0 = blockIdx.x * 128;
  int y0 = blockIdx.y * 128;
  int b = blockIdx.z;
  const ushort* Ap = U + (size_t)y0 * DQ;
  const ushort* Bp = xb + ((size_t)b * SQ + s0) * DQ;
  f32x4 acc[4][4];
  #pragma unroll
  for (int i = 0; i < 4; ++i)
    #pragma unroll
    for (int j = 0; j < 4; ++j) acc[i][j] = fz4;
  int lane = tid & 63, wave = tid >> 6;
  int wm = wave & 1, wn = wave >> 1;
  int lr = lane & 15, lg = lane >> 4;

  for (int kc = 0; kc < DQ; kc += 128) {
    __syncthreads();
    #pragma unroll
    for (int it = 0; it < 8; ++it) {
      int gi = tid + it * 256;
      int r = gi >> 4, g = gi & 15;
      int pofs = r * LD + swz_chunk(r, g) * 8;
      *(s16x8*)&sA[pofs] = *(const s16x8*)(Ap + (size_t)r * DQ + kc + g * 8);
      *(s16x8*)&sB[pofs] = *(const s16x8*)(Bp + (size_t)r * DQ + kc + g * 8);
    }
    __syncthreads();
    #pragma unroll
    for (int ks = 0; ks < 4; ++ks) {
      s16x8 af[4], bfr[4];
      #pragma unroll
      for (int i = 0; i < 4; ++i) {
        int row = wm * 64 + i * 16 + lr;
        af[i] = *(const s16x8*)&sA[row * LD + swz_chunk(row, ks * 4 + lg) * 8];
      }
      #pragma unroll
      for (int i = 0; i < 4; ++i) {
        int row = wn * 64 + i * 16 + lr;
        bfr[i] = *(const s16x8*)&sB[row * LD + swz_chunk(row, ks * 4 + lg) * 8];
      }
      #pragma unroll
      for (int i = 0; i < 4; ++i)
        #pragma unroll
        for (int j = 0; j < 4; ++j)
          acc[i][j] = mfma16(af[i], bfr[j], acc[i][j]);
    }
  }
  int rb = wm * 64 + lg * 4;
  int cb_ = wn * 64 + lr;
  int hb = blockIdx.x * 2 + wn;   // 64-col block index in [0,32)

  // row stats: per (i,q), max+sumexp over this wave's 64 cols
  float mxr[4][4];
  #pragma unroll
  for (int i = 0; i < 4; ++i)
    #pragma unroll
    for (int q = 0; q < 4; ++q) {
      float mx = fmaxf(fmaxf(acc[i][0][q], acc[i][1][q]),
                       fmaxf(acc[i][2][q], acc[i][3][q]));
      #pragma unroll
      for (int o = 1; o < 16; o <<= 1) mx = fmaxf(mx, __shfl_xor(mx, o));
      mxr[i][q] = mx;
      float se = 0.f;
      #pragma unroll
      for (int j = 0; j < 4; ++j) se += __expf(acc[i][j][q] - mx);
      #pragma unroll
      for (int o = 1; o < 16; o <<= 1) se += __shfl_xor(se, o);
      int r = y0 + rb + i * 16 + q;
      if (lr == 0 && r < YQ) {
        float* pp = part + ((size_t)(b * YQ + r) * 32 + hb) * 2;
        pp[0] = mx;
        pp[1] = se;
      }
    }

  if (Pb) {
    ushort* out = Pb + (size_t)b * YQ * SQ;
    #pragma unroll
    for (int i = 0; i < 4; ++i)
      #pragma unroll
      for (int j = 0; j < 4; ++j) {
        int col = s0 + cb_ + j * 16;
        #pragma unroll
        for (int q = 0; q < 4; ++q) {
          int r = y0 + rb + i * 16 + q;
          if (r < YQ)
            out[(size_t)r * SQ + col] = f2bf(__expf(acc[i][j][q] - mxr[i][q]));
        }
      }
  } else {
    float* out = sc + (size_t)b * YQ * SQ;
    #pragma unroll
    for (int i = 0; i < 4; ++i)
      #pragma unroll
      for (int j = 0; j < 4; ++j) {
        int col = s0 + cb_ + j * 16;
        #pragma unroll
        for (int q = 0; q < 4; ++q) {
          int r = y0 + rb + i * 16 + q;
          if (r < YQ) out[(size_t)r * SQ + col] = acc[i][j][q];
        }
      }
  }
}

// ---- merge 32 per-row partials -> rowstats {M,1/Z} + per-chunk corr --------
__global__ void k_smfix(const float* __restrict__ part, float* __restrict__ rs,
                        float* __restrict__ rc) {
  int t = blockIdx.x * 256 + threadIdx.x;
  if (t >= BQ * YQ) return;
  const float* pp = part + (size_t)t * 64;
  float M = -3.0e38f;
  #pragma unroll
  for (int h = 0; h < 32; ++h) M = fmaxf(M, pp[h * 2]);
  float Z = 0.f;
  #pragma unroll
  for (int h = 0; h < 32; ++h) Z += __expf(pp[h * 2] - M) * pp[h * 2 + 1];
  float iZ = 1.0f / Z;
  rs[t * 2] = M;
  rs[t * 2 + 1] = iZ;
  if (rc) {
    #pragma unroll
    for (int h = 0; h < 32; ++h)
      rc[(size_t)t * 32 + h] = __expf(pp[h * 2] - M) * iZ;
  }
}

// ---- fallback only: in-place S -> alpha (f32), vectorized ------------------
__global__ void k_alpha(float* __restrict__ a, const float* __restrict__ rs) {
  int r = blockIdx.x;
  float M = rs[r * 2], iZ = rs[r * 2 + 1];
  float* p = a + (size_t)r * SQ;
  int tid = threadIdx.x;
  #pragma unroll
  for (int i = 0; i < 2; ++i) {
    int e = (tid + i * 256) * 4;
    f32x4 v = ld4u(p + e);
    v.x = __expf(v.x - M) * iZ;
    v.y = __expf(v.y - M) * iZ;
    v.z = __expf(v.z - M) * iZ;
    v.w = __expf(v.w - M) * iZ;
    st4u(p + e, v);
  }
}

// ---- PV v2 fused: m = (P*corr) . x ; alpha f32 emitted during staging ------
__launch_bounds__(512, 4)
__global__ void k_pv2(const ushort* __restrict__ Pb, const float* __restrict__ rc,
                      const ushort* __restrict__ xT, float* __restrict__ mo,
                      float* __restrict__ aout) {
  __shared__ ushort sA[128 * 64];
  __shared__ ushort sB[256 * 64];
  const f32x4 fz4 = {0.f, 0.f, 0.f, 0.f};
  int tid = threadIdx.x;
  int d0 = blockIdx.x * 256;
  int y0 = blockIdx.y * 128;
  int b = blockIdx.z;
  int lane = tid & 63, wave = tid >> 6;
  int wm = wave >> 1;
  int wn = wave & 1;
  int lr = lane & 15, lg = lane >> 4;

  const ushort* Ap = Pb + ((size_t)b * YQ + y0) * SQ;
  const ushort* Bp = xT + ((size_t)b * DQ + d0) * SQ;

  f32x4 acc[2][8];
  #pragma unroll
  for (int i = 0; i < 2; ++i)
    #pragma unroll
    for (int j = 0; j < 8; ++j) acc[i][j] = fz4;

  for (int kc = 0; kc < SQ; kc += 64) {
    bool wr_alpha = ((kc >> 10) == (int)blockIdx.x);
    int hb = kc >> 6;
    // stage A: scale P by corr, repack bf16; optionally write alpha f32
    #pragma unroll
    for (int p = 0; p < 2; ++p) {
      int u = tid + p * 512;
      int r = u >> 3, c = u & 7;
      int y = y0 + r;
      ushort4 h0 = make_ushort4(0, 0, 0, 0), h1 = make_ushort4(0, 0, 0, 0);
      if (y < YQ) {
        size_t base = (size_t)r * SQ + kc + c * 8;
        s16x8 v = *(const s16x8*)(Ap + base);
        float corr = rc[((size_t)(b * YQ + y)) * 32 + hb];
        float pf[8];
        #pragma unroll
        for (int k2 = 0; k2 < 8; ++k2) pf[k2] = bf2f((ushort)v[k2]) * corr;
        if (wr_alpha) {
          float* ao = aout + ((size_t)b * YQ + y) * SQ + kc + c * 8;
          f32x4 w0 = {pf[0], pf[1], pf[2], pf[3]};
          f32x4 w1 = {pf[4], pf[5], pf[6], pf[7]};
          st4u(ao, w0);
          st4u(ao + 4, w1);
        }
        h0 = make_ushort4(f2bf(pf[0]), f2bf(pf[1]), f2bf(pf[2]), f2bf(pf[3]));
        h1 = make_ushort4(f2bf(pf[4]), f2bf(pf[5]), f2bf(pf[6]), f2bf(pf[7]));
      }
      int pofs = r * 64 + swz3(r, c) * 8;
      *(ushort4*)&sA[pofs] = h0;
      *(ushort4*)&sA[pofs + 4] = h1;
    }
    // stage B
    #pragma unroll
    for (int p = 0; p < 4; ++p) {
      int u = tid + p * 512;
      int r = u >> 3, c = u & 7;
      *(s16x8*)&sB[r * 64 + swz3(r, c) * 8] =
          *(const s16x8*)(Bp + (size_t)r * SQ + kc + c * 8);
    }
    __syncthreads();
    #pragma unroll
    for (int ks = 0; ks < 2; ++ks) {
      s16x8 af[2];
      #pragma unroll
      for (int i = 0; i < 2; ++i) {
        int row = wm * 32 + i * 16 + lr;
        af[i] = *(const s16x8*)&sA[row * 64 + swz3(row, ks * 4 + lg) * 8];
      }
      #pragma unroll
      for (int j = 0; j < 8; ++j) {
        int row = wn * 128 + j * 16 + lr;
        s16x8 bf = *(const s16x8*)&sB[row * 64 + swz3(row, ks * 4 + lg) * 8];
        acc[0][j] = mfma16(af[0], bf, acc[0][j]);
        acc[1][j] = mfma16(af[1], bf, acc[1][j]);
      }
    }
    __syncthreads();
  }

  float* out = mo + (size_t)b * YQ * DQ;
  #pragma unroll
  for (int i = 0; i < 2; ++i)
    #pragma unroll
    for (int q = 0; q < 4; ++q) {
      int r = y0 + wm * 32 + i * 16 + lg * 4 + q;
      if (r >= YQ) continue;
      #pragma unroll
      for (int j = 0; j < 8; ++j) {
        int col = d0 + wn * 128 + j * 16 + lr;
        out[(size_t)r * DQ + col] = acc[i][j][q];
      }
    }
}

// ---- PV fallback (small ws): m = alpha(f32,d_out) . x ----------------------
__launch_bounds__(256, 2)
__global__ void k_pv(const float* __restrict__ alpha, const ushort* __restrict__ xT,
                     float* __restrict__ mo) {
  __shared__ ushort sA[128 * LD];
  __shared__ ushort sB[128 * LD];
  const f32x4 fz4 = {0.f, 0.f, 0.f, 0.f};
  int tid = threadIdx.x;
  int d0 = blockIdx.x * 128;
  int y0 = blockIdx.y * 128;
  int b = blockIdx.z;
  const float* Ap = alpha + ((size_t)b * YQ + y0) * SQ;
  const ushort* Bp = xT + ((size_t)b * DQ + d0) * SQ;
  f32x4 acc[4][4];
  #pragma unroll
  for (int i = 0; i < 4; ++i)
    #pragma unroll
    for (int j = 0; j < 4; ++j) acc[i][j] = fz4;
  int lane = tid & 63, wave = tid >> 6;
  int wm = wave & 1, wn = wave >> 1;
  int lr = lane & 15, lg = lane >> 4;

  for (int kc = 0; kc < SQ; kc += 128) {
    __syncthreads();
    #pragma unroll
    for (int it = 0; it < 8; ++it) {
      int gi = tid + it * 256;
      int r = gi >> 4, g = gi & 15;
      int y = y0 + r;
      int pofs = r * LD + swz_chunk(r, g) * 8;
      ushort4 h0 = make_ushort4(0, 0, 0, 0), h1 = make_ushort4(0, 0, 0, 0);
      if (y < YQ) {
        f32x4 v0 = ld4u(Ap + (size_t)r * SQ + kc + g * 8);
        f32x4 v1 = ld4u(Ap + (size_t)r * SQ + kc + g * 8 + 4);
        h0 = make_ushort4(f2bf(v0.x), f2bf(v0.y), f2bf(v0.z), f2bf(v0.w));
        h1 = make_ushort4(f2bf(v1.x), f2bf(v1.y), f2bf(v1.z), f2bf(v1.w));
      }
      *(ushort4*)&sA[pofs] = h0;
      *(ushort4*)&sA[pofs + 4] = h1;
      *(s16x8*)&sB[pofs] = *(const s16x8*)(Bp + (size_t)r * SQ + kc + g * 8);
    }
    __syncthreads();
    #pragma unroll
    for (int ks = 0; ks < 4; ++ks) {
      s16x8 af[4], bfr[4];
      #pragma unroll
      for (int i = 0; i < 4; ++i) {
        int row = wm * 64 + i * 16 + lr;
        af[i] = *(const s16x8*)&sA[row * LD + swz_chunk(row, ks * 4 + lg) * 8];
      }
      #pragma unroll
      for (int i = 0; i < 4; ++i) {
        int row = wn * 64 + i * 16 + lr;
        bfr[i] = *(const s16x8*)&sB[row * LD + swz_chunk(row, ks * 4 + lg) * 8];
      }
      #pragma unroll
      for (int i = 0; i < 4; ++i)
        #pragma unroll
        for (int j = 0; j < 4; ++j)
          acc[i][j] = mfma16(af[i], bfr[j], acc[i][j]);
    }
  }
  float* out = mo + (size_t)b * YQ * DQ;
  int rb = wm * 64 + lg * 4;
  int cb_ = wn * 64 + lr;
  #pragma unroll
  for (int i = 0; i < 4; ++i)
    #pragma unroll
    for (int j = 0; j < 4; ++j) {
      int col = d0 + cb_ + j * 16;
      #pragma unroll
      for (int q = 0; q < 4; ++q) {
        int r = y0 + rb + i * 16 + q;
        if (r < YQ) out[(size_t)r * DQ + col] = acc[i][j][q];
      }
    }
}

// ------- y = m . final_w + b ; per-block loss partial (NO hot atomics) ------
__global__ void k_final(const float* __restrict__ m_in, const float* __restrict__ fw,
                        const float* __restrict__ fb, const float* __restrict__ tgt,
                        float* __restrict__ yo, float* __restrict__ part) {
  int y = blockIdx.x;
  int lane = threadIdx.x & 63;
  int b = threadIdx.x >> 6;
  const float* mp = m_in + ((size_t)b * YQ + y) * DQ;
  const float* wp = fw + (size_t)y * DQ;
  float s = 0.f;
  #pragma unroll
  for (int i = 0; i < 8; ++i) {
    int e = lane + i * 64;
    s += mp[e] * wp[e];
  }
  #pragma unroll
  for (int o = 32; o > 0; o >>= 1) s += __shfl_xor(s, o);
  __shared__ float pl[4];
  if (lane == 0) {
    float yv = s + fb[y];
    yo[(size_t)b * YQ + y] = yv;
    float t = tgt[(size_t)b * YQ + y];
    pl[b] = fmaxf(yv, 0.f) - yv * t + log1pf(__expf(-fabsf(yv)));
  }
  __syncthreads();
  if (threadIdx.x == 0)
    part[y] = (pl[0] + pl[1]) + (pl[2] + pl[3]);
}

// ------- reduce 8922 per-label partials -> mean loss ------------------------
__global__ void k_loss_fin(const float* __restrict__ part, float* __restrict__ out) {
  int tid = threadIdx.x;
  float s = 0.f;
  for (int i = tid; i < YQ; i += 256) s += part[i];
  #pragma unroll
  for (int o = 32; o > 0; o >>= 1) s += __shfl_xor(s, o);
  __shared__ float red[4];
  int lane = tid & 63, wave = tid >> 6;
  if (lane == 0) red[wave] = s;
  __syncthreads();
  if (tid == 0)
    out[0] = ((red[0] + red[1]) + (red[2] + red[3])) * (1.0f / (float)(BQ * YQ));
}

extern "C" void kernel_launch(void* const* d_in, const int* in_sizes, int n_in,
                              void* d_out, int out_size, void* d_ws, size_t ws_size,
                              hipStream_t stream) {
  const float* x      = (const float*)d_in[0];
  const float* target = (const float*)d_in[1];
  const int*   c2t    = (const int*)d_in[2];
  const float* embed  = (const float*)d_in[3];
  const float* cw     = (const float*)d_in[4];
  const float* cb     = (const float*)d_in[5];
  const float* fw     = (const float*)d_in[6];
  const float* fb     = (const float*)d_in[7];

  char* ws = (char*)d_ws;
  ushort* xb   = (ushort*)(ws);                 //  8,388,608 B
  ushort* xT   = (ushort*)(ws + 8388608);       //  8,388,608 B
  ushort* Wp   = (ushort*)(ws + 16777216);      //  1,179,648 B
  ushort* U    = (ushort*)(ws + 17956864);      //  9,175,040 B
  float* lpart = (float*)(ws + 27131904);       //  35,688 B
  float* part  = (float*)(ws + 27167744);       //  9,136,128 B  (35688*64*4)
  float* rst   = (float*)(ws + 36303872);       //    285,504 B  (35688*2*4)
  float* rc    = (float*)(ws + 36589568);       //  4,568,064 B  (35688*32*4)
  // rc ends at 41,157,632 (R10/R11 overlap bug fixed in R12).
  const size_t PB_OFF = 41157632;
  const size_t NEED_F = PB_OFF + (size_t)BQ * YQ * SQ * 2;   // ~187.4 MB
  bool fused = (ws_size >= NEED_F);
  ushort* Pb = fused ? (ushort*)(ws + PB_OFF) : (ushort*)0;

  float* out       = (float*)d_out;
  float* out_y     = out;                               // [B][Y]
  float* out_loss  = out + (size_t)BQ * YQ;             // scalar
  float* out_alpha = out + (size_t)BQ * YQ + 1;         // [B][Y][S]
  float* out_m     = out_alpha + (size_t)BQ * YQ * SQ;  // [B][Y][D]

  hipMemsetAsync(U, 0, (size_t)YPAD * DQ * 2, stream);

  k_prep_x<<<dim3(SQ / 64, DQ / 64, BQ), 256, 0, stream>>>(x, xb, xT);
  k_pack_w<<<dim3((KQ * DQ * EP + 255) / 256), 256, 0, stream>>>(cw, Wp);
  k_conv<<<dim3(4, (YQ + 3) / 4), 256, 0, stream>>>(c2t, embed, Wp, cb, U);
  k_scores<<<dim3(SQ / 128, (YQ + 127) / 128, BQ), 256, 0, stream>>>(
      U, xb, Pb, out_alpha, part);
  k_smfix<<<dim3((BQ * YQ + 255) / 256), 256, 0, stream>>>(part, rst,
                                                           fused ? rc : (float*)0);
  if (fused) {
    k_pv2<<<dim3(DQ / 256, (YQ + 127) / 128, BQ), 512, 0, stream>>>(
        Pb, rc, xT, out_m, out_alpha);
  } else {
    k_alpha<<<dim3(BQ * YQ), 256, 0, stream>>>(out_alpha, rst);
    k_pv<<<dim3(DQ / 128, (YQ + 127) / 128, BQ), 256, 0, stream>>>(
        out_alpha, xT, out_m);
  }
  k_final<<<dim3(YQ), 256, 0, stream>>>(out_m, fw, fb, target, out_y, lpart);
  k_loss_fin<<<1, 256, 0, stream>>>(lpart, out_loss);
}

// Round 15
// 810.843 us; speedup vs baseline: 1.0262x; 1.0262x over previous
//
#include <hip/hip_runtime.h>
#include <math.h>

#define BQ 4
#define SQ 2048
#define DQ 512
#define YQ 8922
#define TQ 32
#define EQ 100
#define EP 128      // E padded for MFMA K-steps
#define KQ 9
#define LD 128      // LDS leading dim (bf16) = 256B rows, 4-bit XOR swizzle
#define YPAD 8960

typedef float f32x4 __attribute__((ext_vector_type(4)));
typedef short s16x8 __attribute__((ext_vector_type(8)));

static __device__ __forceinline__ f32x4 mfma16(s16x8 a, s16x8 b, f32x4 c) {
  return __builtin_amdgcn_mfma_f32_16x16x32_bf16(a, b, c, 0, 0, 0);
}

static __device__ __forceinline__ ushort f2bf(float f) {
  union { float f; unsigned u; } v; v.f = f;
  unsigned r = (v.u + 0x7FFFu + ((v.u >> 16) & 1u)) >> 16;
  return (ushort)r;
}

static __device__ __forceinline__ float bf2f(ushort h) {
  union { unsigned u; float f; } v; v.u = ((unsigned)h) << 16; return v.f;
}

// unaligned (4B) 16-byte load/store
static __device__ __forceinline__ f32x4 ld4u(const float* p) {
  f32x4 v; __builtin_memcpy(&v, p, 16); return v;
}
static __device__ __forceinline__ void st4u(float* p, f32x4 v) {
  __builtin_memcpy(p, &v, 16);
}

// 4-bit XOR swizzle for 128-elem (256B) rows: 16 chunks (R3-proven)
static __device__ __forceinline__ int swz_chunk(int row, int chunk) {
  return chunk ^ (row & 15);
}
// 3-bit XOR swizzle for 64-elem (128B) rows: 8 chunks (pv2/R13-proven)
static __device__ __forceinline__ int swz3(int row, int chunk) {
  return chunk ^ (row & 7);
}

// ---- prep: x -> bf16 [B][S][D] and transposed [B][D][S]; vectorized --------
__global__ void k_prep_x(const float* __restrict__ x, ushort* __restrict__ xb,
                         ushort* __restrict__ xT) {
  __shared__ ushort sm[64][66];
  int b = blockIdx.z;
  int s0 = blockIdx.x * 64;
  int d0 = blockIdx.y * 64;
  int tid = threadIdx.x;
  int sr = tid >> 4;
  int c4 = (tid & 15) * 4;
  #pragma unroll
  for (int it = 0; it < 4; ++it) {
    int s = sr + it * 16;
    f32x4 v = *(const f32x4*)(x + ((size_t)b * SQ + s0 + s) * DQ + d0 + c4);
    ushort4 h = make_ushort4(f2bf(v.x), f2bf(v.y), f2bf(v.z), f2bf(v.w));
    *(ushort4*)(xb + ((size_t)b * SQ + s0 + s) * DQ + d0 + c4) = h;
    sm[s][c4] = h.x; sm[s][c4 + 1] = h.y; sm[s][c4 + 2] = h.z; sm[s][c4 + 3] = h.w;
  }
  __syncthreads();
  #pragma unroll
  for (int it = 0; it < 4; ++it) {
    int d = sr + it * 16;
    ushort4 h;
    h.x = sm[c4][d]; h.y = sm[c4 + 1][d]; h.z = sm[c4 + 2][d]; h.w = sm[c4 + 3][d];
    *(ushort4*)(xT + ((size_t)b * DQ + d0 + d) * SQ + s0 + c4) = h;
  }
}

// ---------------- pack conv_w [D][E][K] -> Wp bf16 [K][D][EP] (e>=100 -> 0) --
__global__ void k_pack_w(const float* __restrict__ cw, ushort* __restrict__ Wp) {
  int i = blockIdx.x * 256 + threadIdx.x;
  if (i >= KQ * DQ * EP) return;
  int e = i & (EP - 1);
  int d = (i >> 7) & (DQ - 1);
  int kk = i >> 16;
  float v = (e < EQ) ? cw[((size_t)d * EQ + e) * KQ + kk] : 0.f;
  Wp[i] = f2bf(v);
}

// ---- conv + maxpool + tanh + scale -> U bf16 [YQ][D] -----------------------
// R13-exact (368us): 48 KB LDS (sB [128][64], kk split into 2 e-halves) ->
// 3 blocks/CU. R14's 4-block variant regressed (64B sB rows -> 3x conflicts).
__launch_bounds__(256, 3)
__global__ void k_conv(const int* __restrict__ c2t, const float* __restrict__ embed,
                       const ushort* __restrict__ Wp, const float* __restrict__ cb,
                       ushort* __restrict__ U) {
  __shared__ ushort sA[4 * TQ * LD];   // 32 KB: 4 labels x 32 t x 128 e
  __shared__ ushort sB[128 * 64];      // 16 KB: 128 d x 64 e (one kk-half)
  const f32x4 fz4 = {0.f, 0.f, 0.f, 0.f};
  const s16x8 sz8 = {0, 0, 0, 0, 0, 0, 0, 0};
  int tid = threadIdx.x;
  int d0 = blockIdx.x * 128;
  int y0 = blockIdx.y * 4;
  int lane = tid & 63, wave = tid >> 6;
  int wm = wave & 1, wn = wave >> 1;
  int lr = lane & 15, lg = lane >> 4;

  // stage all title embeddings for 4 labels: [4*32] rows x [LD] bf16, swizzled
  {
    int row = tid >> 1;
    int half = tid & 1;
    int yl = row >> 5, t = row & 31;
    int y = y0 + yl;
    const float* src = 0;
    if (y < YQ) src = embed + (size_t)c2t[y * TQ + t] * EQ + half * 64;
    #pragma unroll
    for (int j = 0; j < 16; ++j) {
      int col = half * 64 + j * 4;
      f32x4 v = fz4;
      if (src != 0 && col + 4 <= EQ) v = *(const f32x4*)(src + j * 4);
      ushort4 h = make_ushort4(f2bf(v.x), f2bf(v.y), f2bf(v.z), f2bf(v.w));
      int pc = swz_chunk(row, col >> 3);
      *(ushort4*)&sA[row * LD + pc * 8 + (col & 7)] = h;
    }
  }

  // prologue: stage sB for step 0 (kk=0, e-half 0) via registers
  s16x8 breg[4];
  {
    const ushort* src = Wp + (size_t)d0 * EP;
    #pragma unroll
    for (int p = 0; p < 4; ++p) {
      int gi = tid + p * 256, r = gi >> 3, c = gi & 7;
      breg[p] = *(const s16x8*)(src + (size_t)r * EP + c * 8);
    }
    #pragma unroll
    for (int p = 0; p < 4; ++p) {
      int gi = tid + p * 256, r = gi >> 3, c = gi & 7;
      *(s16x8*)&sB[r * 64 + swz3(r, c) * 8] = breg[p];
    }
  }
  __syncthreads();

  f32x4 acc[4][4];
  #pragma unroll
  for (int i = 0; i < 4; ++i)
    #pragma unroll
    for (int j = 0; j < 4; ++j) acc[i][j] = fz4;

  for (int step = 0; step < 2 * KQ; ++step) {
    int kk = step >> 1, h = step & 1;
    // T14: issue next-step weight loads into regs BEFORE compute
    if (step + 1 < 2 * KQ) {
      int kk2 = (step + 1) >> 1, h2 = (step + 1) & 1;
      const ushort* src = Wp + ((size_t)kk2 * DQ + d0) * EP + h2 * 64;
      #pragma unroll
      for (int p = 0; p < 4; ++p) {
        int gi = tid + p * 256, r = gi >> 3, c = gi & 7;
        breg[p] = *(const s16x8*)(src + (size_t)r * EP + c * 8);
      }
    }
    #pragma unroll
    for (int e2 = 0; e2 < 2; ++e2) {
      int ee = h * 2 + e2;
      s16x8 af[4], bfr[4];
      #pragma unroll
      for (int i = 0; i < 4; ++i) {
        int rowm = wm * 64 + i * 16 + lr;
        int yl = rowm >> 5;
        int ts = (rowm & 31) + kk - 4;   // shifted time index
        s16x8 a = sz8;
        if ((unsigned)ts < (unsigned)TQ) {
          int row = yl * TQ + ts;
          a = *(const s16x8*)&sA[row * LD + swz_chunk(row, ee * 4 + lg) * 8];
        }
        af[i] = a;
      }
      #pragma unroll
      for (int i = 0; i < 4; ++i) {
        int row = wn * 64 + i * 16 + lr;
        bfr[i] = *(const s16x8*)&sB[row * 64 + swz3(row, e2 * 4 + lg) * 8];
      }
      #pragma unroll
      for (int i = 0; i < 4; ++i)
        #pragma unroll
        for (int j = 0; j < 4; ++j)
          acc[i][j] = mfma16(af[i], bfr[j], acc[i][j]);
    }
    __syncthreads();           // all waves done reading sB for this step
    if (step + 1 < 2 * KQ) {
      #pragma unroll
      for (int p = 0; p < 4; ++p) {
        int gi = tid + p * 256, r = gi >> 3, c = gi & 7;
        *(s16x8*)&sB[r * 64 + swz3(r, c) * 8] = breg[p];
      }
      __syncthreads();         // sB(step+1) visible
    }
  }

  // in-register epilogue: maxpool over t via in-lane fmax + shfl, tanh, scale
  const float scl = 0.04419417382415922f;   // 1/sqrt(D)
  #pragma unroll
  for (int L2 = 0; L2 < 2; ++L2) {
    int y = y0 + wm * 2 + L2;
    #pragma unroll
    for (int j = 0; j < 4; ++j) {
      float mx = -3.0e38f;
      #pragma unroll
      for (int ii = 0; ii < 2; ++ii)
        #pragma unroll
        for (int q = 0; q < 4; ++q)
          mx = fmaxf(mx, acc[L2 * 2 + ii][j][q]);
      mx = fmaxf(mx, __shfl_xor(mx, 16));
      mx = fmaxf(mx, __shfl_xor(mx, 32));
      if (lane < 16 && y < YQ) {
        int col = d0 + wn * 64 + j * 16 + lane;
        U[(size_t)y * DQ + col] = f2bf(tanhf(mx + cb[col]) * scl);
      }
    }
  }
}

// ---- scores: U . xb^T -> P=exp(S-Mloc) bf16 (fused) or raw S f32 (fallback)
//      + per-(row,64col) {max,sumexp} partials --------------------------------
__launch_bounds__(256, 2)
__global__ void k_scores(const ushort* __restrict__ U, const ushort* __restrict__ xb,
                         ushort* __restrict__ Pb, float* __restrict__ sc,
                         float* __restrict__ part) {
  __shared__ ushort sA[128 * LD];
  __shared__ ushort sB[128 * LD];
  const f32x4 fz4 = {0.f, 0.f, 0.f, 0.f};
  int tid = threadIdx.x;
  int s0 = blockIdx.x * 128;
  int y0 = blockIdx.y * 128;
  int b = blockIdx.z;
  const ushort* Ap = U + (size_t)y0 * DQ;
  const ushort* Bp = xb + ((size_t)b * SQ + s0) * DQ;
  f32x4 acc[4][4];
  #pragma unroll
  for (int i = 0; i < 4; ++i)
    #pragma unroll
    for (int j = 0; j < 4; ++j) acc[i][j] = fz4;
  int lane = tid & 63, wave = tid >> 6;
  int wm = wave & 1, wn = wave >> 1;
  int lr = lane & 15, lg = lane >> 4;

  for (int kc = 0; kc < DQ; kc += 128) {
    __syncthreads();
    #pragma unroll
    for (int it = 0; it < 8; ++it) {
      int gi = tid + it * 256;
      int r = gi >> 4, g = gi & 15;
      int pofs = r * LD + swz_chunk(r, g) * 8;
      *(s16x8*)&sA[pofs] = *(const s16x8*)(Ap + (size_t)r * DQ + kc + g * 8);
      *(s16x8*)&sB[pofs] = *(const s16x8*)(Bp + (size_t)r * DQ + kc + g * 8);
    }
    __syncthreads();
    #pragma unroll
    for (int ks = 0; ks < 4; ++ks) {
      s16x8 af[4], bfr[4];
      #pragma unroll
      for (int i = 0; i < 4; ++i) {
        int row = wm * 64 + i * 16 + lr;
        af[i] = *(const s16x8*)&sA[row * LD + swz_chunk(row, ks * 4 + lg) * 8];
      }
      #pragma unroll
      for (int i = 0; i < 4; ++i) {
        int row = wn * 64 + i * 16 + lr;
        bfr[i] = *(const s16x8*)&sB[row * LD + swz_chunk(row, ks * 4 + lg) * 8];
      }
      #pragma unroll
      for (int i = 0; i < 4; ++i)
        #pragma unroll
        for (int j = 0; j < 4; ++j)
          acc[i][j] = mfma16(af[i], bfr[j], acc[i][j]);
    }
  }
  int rb = wm * 64 + lg * 4;
  int cb_ = wn * 64 + lr;
  int hb = blockIdx.x * 2 + wn;   // 64-col block index in [0,32)

  // row stats: per (i,q), max+sumexp over this wave's 64 cols
  float mxr[4][4];
  #pragma unroll
  for (int i = 0; i < 4; ++i)
    #pragma unroll
    for (int q = 0; q < 4; ++q) {
      float mx = fmaxf(fmaxf(acc[i][0][q], acc[i][1][q]),
                       fmaxf(acc[i][2][q], acc[i][3][q]));
      #pragma unroll
      for (int o = 1; o < 16; o <<= 1) mx = fmaxf(mx, __shfl_xor(mx, o));
      mxr[i][q] = mx;
      float se = 0.f;
      #pragma unroll
      for (int j = 0; j < 4; ++j) se += __expf(acc[i][j][q] - mx);
      #pragma unroll
      for (int o = 1; o < 16; o <<= 1) se += __shfl_xor(se, o);
      int r = y0 + rb + i * 16 + q;
      if (lr == 0 && r < YQ) {
        float* pp = part + ((size_t)(b * YQ + r) * 32 + hb) * 2;
        pp[0] = mx;
        pp[1] = se;
      }
    }

  if (Pb) {
    ushort* out = Pb + (size_t)b * YQ * SQ;
    #pragma unroll
    for (int i = 0; i < 4; ++i)
      #pragma unroll
      for (int j = 0; j < 4; ++j) {
        int col = s0 + cb_ + j * 16;
        #pragma unroll
        for (int q = 0; q < 4; ++q) {
          int r = y0 + rb + i * 16 + q;
          if (r < YQ)
            out[(size_t)r * SQ + col] = f2bf(__expf(acc[i][j][q] - mxr[i][q]));
        }
      }
  } else {
    float* out = sc + (size_t)b * YQ * SQ;
    #pragma unroll
    for (int i = 0; i < 4; ++i)
      #pragma unroll
      for (int j = 0; j < 4; ++j) {
        int col = s0 + cb_ + j * 16;
        #pragma unroll
        for (int q = 0; q < 4; ++q) {
          int r = y0 + rb + i * 16 + q;
          if (r < YQ) out[(size_t)r * SQ + col] = acc[i][j][q];
        }
      }
  }
}

// ---- merge 32 per-row partials -> rowstats {M,1/Z} + per-chunk corr --------
__global__ void k_smfix(const float* __restrict__ part, float* __restrict__ rs,
                        float* __restrict__ rc) {
  int t = blockIdx.x * 256 + threadIdx.x;
  if (t >= BQ * YQ) return;
  const float* pp = part + (size_t)t * 64;
  float M = -3.0e38f;
  #pragma unroll
  for (int h = 0; h < 32; ++h) M = fmaxf(M, pp[h * 2]);
  float Z = 0.f;
  #pragma unroll
  for (int h = 0; h < 32; ++h) Z += __expf(pp[h * 2] - M) * pp[h * 2 + 1];
  float iZ = 1.0f / Z;
  rs[t * 2] = M;
  rs[t * 2 + 1] = iZ;
  if (rc) {
    #pragma unroll
    for (int h = 0; h < 32; ++h)
      rc[(size_t)t * 32 + h] = __expf(pp[h * 2] - M) * iZ;
  }
}

// ---- fallback only: in-place S -> alpha (f32), vectorized ------------------
__global__ void k_alpha(float* __restrict__ a, const float* __restrict__ rs) {
  int r = blockIdx.x;
  float M = rs[r * 2], iZ = rs[r * 2 + 1];
  float* p = a + (size_t)r * SQ;
  int tid = threadIdx.x;
  #pragma unroll
  for (int i = 0; i < 2; ++i) {
    int e = (tid + i * 256) * 4;
    f32x4 v = ld4u(p + e);
    v.x = __expf(v.x - M) * iZ;
    v.y = __expf(v.y - M) * iZ;
    v.z = __expf(v.z - M) * iZ;
    v.w = __expf(v.w - M) * iZ;
    st4u(p + e, v);
  }
}

// ---- PV v2 fused: m = (P*corr) . x ; alpha f32 emitted during staging ------
// R15: XCD-chunked 1D grid (560 = 8 XCDs x 70). Each XCD owns all 70
// y0-tiles of one (d0,b) pair -> its 1MB xT B-panel stays L2-resident.
__launch_bounds__(512, 4)
__global__ void k_pv2(const ushort* __restrict__ Pb, const float* __restrict__ rc,
                      const ushort* __restrict__ xT, float* __restrict__ mo,
                      float* __restrict__ aout) {
  __shared__ ushort sA[128 * 64];
  __shared__ ushort sB[256 * 64];
  const f32x4 fz4 = {0.f, 0.f, 0.f, 0.f};
  int tid = threadIdx.x;
  // XCD-chunked remap: HW assigns block i -> XCD i%8; job = (i%8)*70 + i/8
  // job ordered (d0i,b) slow, y0i fast -> one (d0i,b) pair per XCD.
  int job = ((int)blockIdx.x % 8) * 70 + (int)blockIdx.x / 8;
  int y0i = job % 70;
  int pair = job / 70;          // 0..7
  int d0i = pair >> 2;          // 0..1
  int b = pair & 3;             // 0..3
  int d0 = d0i * 256;
  int y0 = y0i * 128;
  int lane = tid & 63, wave = tid >> 6;
  int wm = wave >> 1;
  int wn = wave & 1;
  int lr = lane & 15, lg = lane >> 4;

  const ushort* Ap = Pb + ((size_t)b * YQ + y0) * SQ;
  const ushort* Bp = xT + ((size_t)b * DQ + d0) * SQ;

  f32x4 acc[2][8];
  #pragma unroll
  for (int i = 0; i < 2; ++i)
    #pragma unroll
    for (int j = 0; j < 8; ++j) acc[i][j] = fz4;

  for (int kc = 0; kc < SQ; kc += 64) {
    bool wr_alpha = ((kc >> 10) == d0i);   // distribute alpha write by d0i
    int hb = kc >> 6;
    // stage A: scale P by corr, repack bf16; optionally write alpha f32
    #pragma unroll
    for (int p = 0; p < 2; ++p) {
      int u = tid + p * 512;
      int r = u >> 3, c = u & 7;
      int y = y0 + r;
      ushort4 h0 = make_ushort4(0, 0, 0, 0), h1 = make_ushort4(0, 0, 0, 0);
      if (y < YQ) {
        size_t base = (size_t)r * SQ + kc + c * 8;
        s16x8 v = *(const s16x8*)(Ap + base);
        float corr = rc[((size_t)(b * YQ + y)) * 32 + hb];
        float pf[8];
        #pragma unroll
        for (int k2 = 0; k2 < 8; ++k2) pf[k2] = bf2f((ushort)v[k2]) * corr;
        if (wr_alpha) {
          float* ao = aout + ((size_t)b * YQ + y) * SQ + kc + c * 8;
          f32x4 w0 = {pf[0], pf[1], pf[2], pf[3]};
          f32x4 w1 = {pf[4], pf[5], pf[6], pf[7]};
          st4u(ao, w0);
          st4u(ao + 4, w1);
        }
        h0 = make_ushort4(f2bf(pf[0]), f2bf(pf[1]), f2bf(pf[2]), f2bf(pf[3]));
        h1 = make_ushort4(f2bf(pf[4]), f2bf(pf[5]), f2bf(pf[6]), f2bf(pf[7]));
      }
      int pofs = r * 64 + swz3(r, c) * 8;
      *(ushort4*)&sA[pofs] = h0;
      *(ushort4*)&sA[pofs + 4] = h1;
    }
    // stage B
    #pragma unroll
    for (int p = 0; p < 4; ++p) {
      int u = tid + p * 512;
      int r = u >> 3, c = u & 7;
      *(s16x8*)&sB[r * 64 + swz3(r, c) * 8] =
          *(const s16x8*)(Bp + (size_t)r * SQ + kc + c * 8);
    }
    __syncthreads();
    #pragma unroll
    for (int ks = 0; ks < 2; ++ks) {
      s16x8 af[2];
      #pragma unroll
      for (int i = 0; i < 2; ++i) {
        int row = wm * 32 + i * 16 + lr;
        af[i] = *(const s16x8*)&sA[row * 64 + swz3(row, ks * 4 + lg) * 8];
      }
      #pragma unroll
      for (int j = 0; j < 8; ++j) {
        int row = wn * 128 + j * 16 + lr;
        s16x8 bf = *(const s16x8*)&sB[row * 64 + swz3(row, ks * 4 + lg) * 8];
        acc[0][j] = mfma16(af[0], bf, acc[0][j]);
        acc[1][j] = mfma16(af[1], bf, acc[1][j]);
      }
    }
    __syncthreads();
  }

  float* out = mo + (size_t)b * YQ * DQ;
  #pragma unroll
  for (int i = 0; i < 2; ++i)
    #pragma unroll
    for (int q = 0; q < 4; ++q) {
      int r = y0 + wm * 32 + i * 16 + lg * 4 + q;
      if (r >= YQ) continue;
      #pragma unroll
      for (int j = 0; j < 8; ++j) {
        int col = d0 + wn * 128 + j * 16 + lr;
        out[(size_t)r * DQ + col] = acc[i][j][q];
      }
    }
}

// ---- PV fallback (small ws): m = alpha(f32,d_out) . x ----------------------
__launch_bounds__(256, 2)
__global__ void k_pv(const float* __restrict__ alpha, const ushort* __restrict__ xT,
                     float* __restrict__ mo) {
  __shared__ ushort sA[128 * LD];
  __shared__ ushort sB[128 * LD];
  const f32x4 fz4 = {0.f, 0.f, 0.f, 0.f};
  int tid = threadIdx.x;
  int d0 = blockIdx.x * 128;
  int y0 = blockIdx.y * 128;
  int b = blockIdx.z;
  const float* Ap = alpha + ((size_t)b * YQ + y0) * SQ;
  const ushort* Bp = xT + ((size_t)b * DQ + d0) * SQ;
  f32x4 acc[4][4];
  #pragma unroll
  for (int i = 0; i < 4; ++i)
    #pragma unroll
    for (int j = 0; j < 4; ++j) acc[i][j] = fz4;
  int lane = tid & 63, wave = tid >> 6;
  int wm = wave & 1, wn = wave >> 1;
  int lr = lane & 15, lg = lane >> 4;

  for (int kc = 0; kc < SQ; kc += 128) {
    __syncthreads();
    #pragma unroll
    for (int it = 0; it < 8; ++it) {
      int gi = tid + it * 256;
      int r = gi >> 4, g = gi & 15;
      int y = y0 + r;
      int pofs = r * LD + swz_chunk(r, g) * 8;
      ushort4 h0 = make_ushort4(0, 0, 0, 0), h1 = make_ushort4(0, 0, 0, 0);
      if (y < YQ) {
        f32x4 v0 = ld4u(Ap + (size_t)r * SQ + kc + g * 8);
        f32x4 v1 = ld4u(Ap + (size_t)r * SQ + kc + g * 8 + 4);
        h0 = make_ushort4(f2bf(v0.x), f2bf(v0.y), f2bf(v0.z), f2bf(v0.w));
        h1 = make_ushort4(f2bf(v1.x), f2bf(v1.y), f2bf(v1.z), f2bf(v1.w));
      }
      *(ushort4*)&sA[pofs] = h0;
      *(ushort4*)&sA[pofs + 4] = h1;
      *(s16x8*)&sB[pofs] = *(const s16x8*)(Bp + (size_t)r * SQ + kc + g * 8);
    }
    __syncthreads();
    #pragma unroll
    for (int ks = 0; ks < 4; ++ks) {
      s16x8 af[4], bfr[4];
      #pragma unroll
      for (int i = 0; i < 4; ++i) {
        int row = wm * 64 + i * 16 + lr;
        af[i] = *(const s16x8*)&sA[row * LD + swz_chunk(row, ks * 4 + lg) * 8];
      }
      #pragma unroll
      for (int i = 0; i < 4; ++i) {
        int row = wn * 64 + i * 16 + lr;
        bfr[i] = *(const s16x8*)&sB[row * LD + swz_chunk(row, ks * 4 + lg) * 8];
      }
      #pragma unroll
      for (int i = 0; i < 4; ++i)
        #pragma unroll
        for (int j = 0; j < 4; ++j)
          acc[i][j] = mfma16(af[i], bfr[j], acc[i][j]);
    }
  }
  float* out = mo + (size_t)b * YQ * DQ;
  int rb = wm * 64 + lg * 4;
  int cb_ = wn * 64 + lr;
  #pragma unroll
  for (int i = 0; i < 4; ++i)
    #pragma unroll
    for (int j = 0; j < 4; ++j) {
      int col = d0 + cb_ + j * 16;
      #pragma unroll
      for (int q = 0; q < 4; ++q) {
        int r = y0 + rb + i * 16 + q;
        if (r < YQ) out[(size_t)r * DQ + col] = acc[i][j][q];
      }
    }
}

// ------- y = m . final_w + b ; per-block loss partial (NO hot atomics) ------
__global__ void k_final(const float* __restrict__ m_in, const float* __restrict__ fw,
                        const float* __restrict__ fb, const float* __restrict__ tgt,
                        float* __restrict__ yo, float* __restrict__ part) {
  int y = blockIdx.x;
  int lane = threadIdx.x & 63;
  int b = threadIdx.x >> 6;
  const float* mp = m_in + ((size_t)b * YQ + y) * DQ;
  const float* wp = fw + (size_t)y * DQ;
  float s = 0.f;
  #pragma unroll
  for (int i = 0; i < 8; ++i) {
    int e = lane + i * 64;
    s += mp[e] * wp[e];
  }
  #pragma unroll
  for (int o = 32; o > 0; o >>= 1) s += __shfl_xor(s, o);
  __shared__ float pl[4];
  if (lane == 0) {
    float yv = s + fb[y];
    yo[(size_t)b * YQ + y] = yv;
    float t = tgt[(size_t)b * YQ + y];
    pl[b] = fmaxf(yv, 0.f) - yv * t + log1pf(__expf(-fabsf(yv)));
  }
  __syncthreads();
  if (threadIdx.x == 0)
    part[y] = (pl[0] + pl[1]) + (pl[2] + pl[3]);
}

// ------- reduce 8922 per-label partials -> mean loss ------------------------
__global__ void k_loss_fin(const float* __restrict__ part, float* __restrict__ out) {
  int tid = threadIdx.x;
  float s = 0.f;
  for (int i = tid; i < YQ; i += 256) s += part[i];
  #pragma unroll
  for (int o = 32; o > 0; o >>= 1) s += __shfl_xor(s, o);
  __shared__ float red[4];
  int lane = tid & 63, wave = tid >> 6;
  if (lane == 0) red[wave] = s;
  __syncthreads();
  if (tid == 0)
    out[0] = ((red[0] + red[1]) + (red[2] + red[3])) * (1.0f / (float)(BQ * YQ));
}

extern "C" void kernel_launch(void* const* d_in, const int* in_sizes, int n_in,
                              void* d_out, int out_size, void* d_ws, size_t ws_size,
                              hipStream_t stream) {
  const float* x      = (const float*)d_in[0];
  const float* target = (const float*)d_in[1];
  const int*   c2t    = (const int*)d_in[2];
  const float* embed  = (const float*)d_in[3];
  const float* cw     = (const float*)d_in[4];
  const float* cb     = (const float*)d_in[5];
  const float* fw     = (const float*)d_in[6];
  const float* fb     = (const float*)d_in[7];

  char* ws = (char*)d_ws;
  ushort* xb   = (ushort*)(ws);                 //  8,388,608 B
  ushort* xT   = (ushort*)(ws + 8388608);       //  8,388,608 B
  ushort* Wp   = (ushort*)(ws + 16777216);      //  1,179,648 B
  ushort* U    = (ushort*)(ws + 17956864);      //  9,175,040 B
  float* lpart = (float*)(ws + 27131904);       //  35,688 B
  float* part  = (float*)(ws + 27167744);       //  9,136,128 B  (35688*64*4)
  float* rst   = (float*)(ws + 36303872);       //    285,504 B  (35688*2*4)
  float* rc    = (float*)(ws + 36589568);       //  4,568,064 B  (35688*32*4)
  // rc ends at 41,157,632 (R10/R11 overlap bug fixed in R12).
  const size_t PB_OFF = 41157632;
  const size_t NEED_F = PB_OFF + (size_t)BQ * YQ * SQ * 2;   // ~187.4 MB
  bool fused = (ws_size >= NEED_F);
  ushort* Pb = fused ? (ushort*)(ws + PB_OFF) : (ushort*)0;

  float* out       = (float*)d_out;
  float* out_y     = out;                               // [B][Y]
  float* out_loss  = out + (size_t)BQ * YQ;             // scalar
  float* out_alpha = out + (size_t)BQ * YQ + 1;         // [B][Y][S]
  float* out_m     = out_alpha + (size_t)BQ * YQ * SQ;  // [B][Y][D]

  hipMemsetAsync(U, 0, (size_t)YPAD * DQ * 2, stream);

  k_prep_x<<<dim3(SQ / 64, DQ / 64, BQ), 256, 0, stream>>>(x, xb, xT);
  k_pack_w<<<dim3((KQ * DQ * EP + 255) / 256), 256, 0, stream>>>(cw, Wp);
  k_conv<<<dim3(4, (YQ + 3) / 4), 256, 0, stream>>>(c2t, embed, Wp, cb, U);
  k_scores<<<dim3(SQ / 128, (YQ + 127) / 128, BQ), 256, 0, stream>>>(
      U, xb, Pb, out_alpha, part);
  k_smfix<<<dim3((BQ * YQ + 255) / 256), 256, 0, stream>>>(part, rst,
                                                           fused ? rc : (float*)0);
  if (fused) {
    k_pv2<<<dim3(560), 512, 0, stream>>>(Pb, rc, xT, out_m, out_alpha);
  } else {
    k_alpha<<<dim3(BQ * YQ), 256, 0, stream>>>(out_alpha, rst);
    k_pv<<<dim3(DQ / 128, (YQ + 127) / 128, BQ), 256, 0, stream>>>(
        out_alpha, xT, out_m);
  }
  k_final<<<dim3(YQ), 256, 0, stream>>>(out_m, fw, fb, target, out_y, lpart);
  k_loss_fin<<<1, 256, 0, stream>>>(lpart, out_loss);
}

// Round 16
// 806.717 us; speedup vs baseline: 1.0315x; 1.0051x over previous
//
#include <hip/hip_runtime.h>
#include <math.h>

#define BQ 4
#define SQ 2048
#define DQ 512
#define YQ 8922
#define TQ 32
#define EQ 100
#define EP 128      // E padded for MFMA K-steps
#define KQ 9
#define LD 128      // LDS leading dim (bf16) = 256B rows, 4-bit XOR swizzle
#define YPAD 8960
#define ZROW 128    // conv sA zero row (all-zero, for out-of-range ts reads)

typedef float f32x4 __attribute__((ext_vector_type(4)));
typedef short s16x8 __attribute__((ext_vector_type(8)));

static __device__ __forceinline__ f32x4 mfma16(s16x8 a, s16x8 b, f32x4 c) {
  return __builtin_amdgcn_mfma_f32_16x16x32_bf16(a, b, c, 0, 0, 0);
}

static __device__ __forceinline__ ushort f2bf(float f) {
  union { float f; unsigned u; } v; v.f = f;
  unsigned r = (v.u + 0x7FFFu + ((v.u >> 16) & 1u)) >> 16;
  return (ushort)r;
}

static __device__ __forceinline__ float bf2f(ushort h) {
  union { unsigned u; float f; } v; v.u = ((unsigned)h) << 16; return v.f;
}

// unaligned (4B) 16-byte load/store
static __device__ __forceinline__ f32x4 ld4u(const float* p) {
  f32x4 v; __builtin_memcpy(&v, p, 16); return v;
}
static __device__ __forceinline__ void st4u(float* p, f32x4 v) {
  __builtin_memcpy(p, &v, 16);
}

// 4-bit XOR swizzle for 128-elem (256B) rows: 16 chunks (R3-proven)
static __device__ __forceinline__ int swz_chunk(int row, int chunk) {
  return chunk ^ (row & 15);
}
// 3-bit XOR swizzle for 64-elem (128B) rows: 8 chunks (pv2/R13-proven)
static __device__ __forceinline__ int swz3(int row, int chunk) {
  return chunk ^ (row & 7);
}

// ---- prep: x -> bf16 [B][S][D] and transposed [B][D][S]; vectorized --------
__global__ void k_prep_x(const float* __restrict__ x, ushort* __restrict__ xb,
                         ushort* __restrict__ xT) {
  __shared__ ushort sm[64][66];
  int b = blockIdx.z;
  int s0 = blockIdx.x * 64;
  int d0 = blockIdx.y * 64;
  int tid = threadIdx.x;
  int sr = tid >> 4;
  int c4 = (tid & 15) * 4;
  #pragma unroll
  for (int it = 0; it < 4; ++it) {
    int s = sr + it * 16;
    f32x4 v = *(const f32x4*)(x + ((size_t)b * SQ + s0 + s) * DQ + d0 + c4);
    ushort4 h = make_ushort4(f2bf(v.x), f2bf(v.y), f2bf(v.z), f2bf(v.w));
    *(ushort4*)(xb + ((size_t)b * SQ + s0 + s) * DQ + d0 + c4) = h;
    sm[s][c4] = h.x; sm[s][c4 + 1] = h.y; sm[s][c4 + 2] = h.z; sm[s][c4 + 3] = h.w;
  }
  __syncthreads();
  #pragma unroll
  for (int it = 0; it < 4; ++it) {
    int d = sr + it * 16;
    ushort4 h;
    h.x = sm[c4][d]; h.y = sm[c4 + 1][d]; h.z = sm[c4 + 2][d]; h.w = sm[c4 + 3][d];
    *(ushort4*)(xT + ((size_t)b * DQ + d0 + d) * SQ + s0 + c4) = h;
  }
}

// ---------------- pack conv_w [D][E][K] -> Wp bf16 [K][D][EP] (e>=100 -> 0) --
__global__ void k_pack_w(const float* __restrict__ cw, ushort* __restrict__ Wp) {
  int i = blockIdx.x * 256 + threadIdx.x;
  if (i >= KQ * DQ * EP) return;
  int e = i & (EP - 1);
  int d = (i >> 7) & (DQ - 1);
  int kk = i >> 16;
  float v = (e < EQ) ? cw[((size_t)d * EQ + e) * KQ + kk] : 0.f;
  Wp[i] = f2bf(v);
}

// ---- conv + maxpool + tanh + scale -> U bf16 [YQ][D] -----------------------
// R13 structure (368us) + R16 zero-row: out-of-range ts reads select a zeroed
// sA row (address cndmask, 1 per frag) instead of 4-VGPR data selects.
__launch_bounds__(256, 3)
__global__ void k_conv(const int* __restrict__ c2t, const float* __restrict__ embed,
                       const ushort* __restrict__ Wp, const float* __restrict__ cb,
                       ushort* __restrict__ U) {
  __shared__ ushort sA[(4 * TQ + 1) * LD];  // 32.25 KB: 128 rows + 1 zero row
  __shared__ ushort sB[128 * 64];           // 16 KB: 128 d x 64 e (one kk-half)
  const f32x4 fz4 = {0.f, 0.f, 0.f, 0.f};
  int tid = threadIdx.x;
  int d0 = blockIdx.x * 128;
  int y0 = blockIdx.y * 4;
  int lane = tid & 63, wave = tid >> 6;
  int wm = wave & 1, wn = wave >> 1;
  int lr = lane & 15, lg = lane >> 4;

  // stage all title embeddings for 4 labels: [4*32] rows x [LD] bf16, swizzled
  {
    int row = tid >> 1;
    int half = tid & 1;
    int yl = row >> 5, t = row & 31;
    int y = y0 + yl;
    const float* src = 0;
    if (y < YQ) src = embed + (size_t)c2t[y * TQ + t] * EQ + half * 64;
    #pragma unroll
    for (int j = 0; j < 16; ++j) {
      int col = half * 64 + j * 4;
      f32x4 v = fz4;
      if (src != 0 && col + 4 <= EQ) v = *(const f32x4*)(src + j * 4);
      ushort4 h = make_ushort4(f2bf(v.x), f2bf(v.y), f2bf(v.z), f2bf(v.w));
      int pc = swz_chunk(row, col >> 3);
      *(ushort4*)&sA[row * LD + pc * 8 + (col & 7)] = h;
    }
    // zero row (index ZROW=128): 128 bf16 = 16 threads x 8
    if (tid < 16) {
      const s16x8 z8 = {0, 0, 0, 0, 0, 0, 0, 0};
      *(s16x8*)&sA[ZROW * LD + tid * 8] = z8;
    }
  }

  // prologue: stage sB for step 0 (kk=0, e-half 0) via registers
  s16x8 breg[4];
  {
    const ushort* src = Wp + (size_t)d0 * EP;
    #pragma unroll
    for (int p = 0; p < 4; ++p) {
      int gi = tid + p * 256, r = gi >> 3, c = gi & 7;
      breg[p] = *(const s16x8*)(src + (size_t)r * EP + c * 8);
    }
    #pragma unroll
    for (int p = 0; p < 4; ++p) {
      int gi = tid + p * 256, r = gi >> 3, c = gi & 7;
      *(s16x8*)&sB[r * 64 + swz3(r, c) * 8] = breg[p];
    }
  }
  __syncthreads();

  f32x4 acc[4][4];
  #pragma unroll
  for (int i = 0; i < 4; ++i)
    #pragma unroll
    for (int j = 0; j < 4; ++j) acc[i][j] = fz4;

  for (int step = 0; step < 2 * KQ; ++step) {
    int kk = step >> 1, h = step & 1;
    // T14: issue next-step weight loads into regs BEFORE compute
    if (step + 1 < 2 * KQ) {
      int kk2 = (step + 1) >> 1, h2 = (step + 1) & 1;
      const ushort* src = Wp + ((size_t)kk2 * DQ + d0) * EP + h2 * 64;
      #pragma unroll
      for (int p = 0; p < 4; ++p) {
        int gi = tid + p * 256, r = gi >> 3, c = gi & 7;
        breg[p] = *(const s16x8*)(src + (size_t)r * EP + c * 8);
      }
    }
    #pragma unroll
    for (int e2 = 0; e2 < 2; ++e2) {
      int ee = h * 2 + e2;
      s16x8 af[4], bfr[4];
      #pragma unroll
      for (int i = 0; i < 4; ++i) {
        int rowm = wm * 64 + i * 16 + lr;
        int yl = rowm >> 5;
        int ts = (rowm & 31) + kk - 4;   // shifted time index
        // zero-row trick: address select, invalid lanes broadcast-read row 128
        int row = ((unsigned)ts < (unsigned)TQ) ? (yl * TQ + ts) : ZROW;
        af[i] = *(const s16x8*)&sA[row * LD + swz_chunk(row, ee * 4 + lg) * 8];
      }
      #pragma unroll
      for (int i = 0; i < 4; ++i) {
        int row = wn * 64 + i * 16 + lr;
        bfr[i] = *(const s16x8*)&sB[row * 64 + swz3(row, e2 * 4 + lg) * 8];
      }
      #pragma unroll
      for (int i = 0; i < 4; ++i)
        #pragma unroll
        for (int j = 0; j < 4; ++j)
          acc[i][j] = mfma16(af[i], bfr[j], acc[i][j]);
    }
    __syncthreads();           // all waves done reading sB for this step
    if (step + 1 < 2 * KQ) {
      #pragma unroll
      for (int p = 0; p < 4; ++p) {
        int gi = tid + p * 256, r = gi >> 3, c = gi & 7;
        *(s16x8*)&sB[r * 64 + swz3(r, c) * 8] = breg[p];
      }
      __syncthreads();         // sB(step+1) visible
    }
  }

  // in-register epilogue: maxpool over t via in-lane fmax + shfl, tanh, scale
  const float scl = 0.04419417382415922f;   // 1/sqrt(D)
  #pragma unroll
  for (int L2 = 0; L2 < 2; ++L2) {
    int y = y0 + wm * 2 + L2;
    #pragma unroll
    for (int j = 0; j < 4; ++j) {
      float mx = -3.0e38f;
      #pragma unroll
      for (int ii = 0; ii < 2; ++ii)
        #pragma unroll
        for (int q = 0; q < 4; ++q)
          mx = fmaxf(mx, acc[L2 * 2 + ii][j][q]);
      mx = fmaxf(mx, __shfl_xor(mx, 16));
      mx = fmaxf(mx, __shfl_xor(mx, 32));
      if (lane < 16 && y < YQ) {
        int col = d0 + wn * 64 + j * 16 + lane;
        U[(size_t)y * DQ + col] = f2bf(tanhf(mx + cb[col]) * scl);
      }
    }
  }
}

// ---- scores: U . xb^T -> P=exp(S-Mloc) bf16 (fused) or raw S f32 (fallback)
//      + per-(row,64col) {max,sumexp} partials --------------------------------
__launch_bounds__(256, 2)
__global__ void k_scores(const ushort* __restrict__ U, const ushort* __restrict__ xb,
                         ushort* __restrict__ Pb, float* __restrict__ sc,
                         float* __restrict__ part) {
  __shared__ ushort sA[128 * LD];
  __shared__ ushort sB[128 * LD];
  const f32x4 fz4 = {0.f, 0.f, 0.f, 0.f};
  int tid = threadIdx.x;
  int s0 = blockIdx.x * 128;
  int y0 = blockIdx.y * 128;
  int b = blockIdx.z;
  const ushort* Ap = U + (size_t)y0 * DQ;
  const ushort* Bp = xb + ((size_t)b * SQ + s0) * DQ;
  f32x4 acc[4][4];
  #pragma unroll
  for (int i = 0; i < 4; ++i)
    #pragma unroll
    for (int j = 0; j < 4; ++j) acc[i][j] = fz4;
  int lane = tid & 63, wave = tid >> 6;
  int wm = wave & 1, wn = wave >> 1;
  int lr = lane & 15, lg = lane >> 4;

  for (int kc = 0; kc < DQ; kc += 128) {
    __syncthreads();
    #pragma unroll
    for (int it = 0; it < 8; ++it) {
      int gi = tid + it * 256;
      int r = gi >> 4, g = gi & 15;
      int pofs = r * LD + swz_chunk(r, g) * 8;
      *(s16x8*)&sA[pofs] = *(const s16x8*)(Ap + (size_t)r * DQ + kc + g * 8);
      *(s16x8*)&sB[pofs] = *(const s16x8*)(Bp + (size_t)r * DQ + kc + g * 8);
    }
    __syncthreads();
    #pragma unroll
    for (int ks = 0; ks < 4; ++ks) {
      s16x8 af[4], bfr[4];
      #pragma unroll
      for (int i = 0; i < 4; ++i) {
        int row = wm * 64 + i * 16 + lr;
        af[i] = *(const s16x8*)&sA[row * LD + swz_chunk(row, ks * 4 + lg) * 8];
      }
      #pragma unroll
      for (int i = 0; i < 4; ++i) {
        int row = wn * 64 + i * 16 + lr;
        bfr[i] = *(const s16x8*)&sB[row * LD + swz_chunk(row, ks * 4 + lg) * 8];
      }
      #pragma unroll
      for (int i = 0; i < 4; ++i)
        #pragma unroll
        for (int j = 0; j < 4; ++j)
          acc[i][j] = mfma16(af[i], bfr[j], acc[i][j]);
    }
  }
  int rb = wm * 64 + lg * 4;
  int cb_ = wn * 64 + lr;
  int hb = blockIdx.x * 2 + wn;   // 64-col block index in [0,32)

  // row stats: per (i,q), max+sumexp over this wave's 64 cols
  float mxr[4][4];
  #pragma unroll
  for (int i = 0; i < 4; ++i)
    #pragma unroll
    for (int q = 0; q < 4; ++q) {
      float mx = fmaxf(fmaxf(acc[i][0][q], acc[i][1][q]),
                       fmaxf(acc[i][2][q], acc[i][3][q]));
      #pragma unroll
      for (int o = 1; o < 16; o <<= 1) mx = fmaxf(mx, __shfl_xor(mx, o));
      mxr[i][q] = mx;
      float se = 0.f;
      #pragma unroll
      for (int j = 0; j < 4; ++j) se += __expf(acc[i][j][q] - mx);
      #pragma unroll
      for (int o = 1; o < 16; o <<= 1) se += __shfl_xor(se, o);
      int r = y0 + rb + i * 16 + q;
      if (lr == 0 && r < YQ) {
        float* pp = part + ((size_t)(b * YQ + r) * 32 + hb) * 2;
        pp[0] = mx;
        pp[1] = se;
      }
    }

  if (Pb) {
    ushort* out = Pb + (size_t)b * YQ * SQ;
    #pragma unroll
    for (int i = 0; i < 4; ++i)
      #pragma unroll
      for (int j = 0; j < 4; ++j) {
        int col = s0 + cb_ + j * 16;
        #pragma unroll
        for (int q = 0; q < 4; ++q) {
          int r = y0 + rb + i * 16 + q;
          if (r < YQ)
            out[(size_t)r * SQ + col] = f2bf(__expf(acc[i][j][q] - mxr[i][q]));
        }
      }
  } else {
    float* out = sc + (size_t)b * YQ * SQ;
    #pragma unroll
    for (int i = 0; i < 4; ++i)
      #pragma unroll
      for (int j = 0; j < 4; ++j) {
        int col = s0 + cb_ + j * 16;
        #pragma unroll
        for (int q = 0; q < 4; ++q) {
          int r = y0 + rb + i * 16 + q;
          if (r < YQ) out[(size_t)r * SQ + col] = acc[i][j][q];
        }
      }
  }
}

// ---- merge 32 per-row partials -> rowstats {M,1/Z} + per-chunk corr --------
__global__ void k_smfix(const float* __restrict__ part, float* __restrict__ rs,
                        float* __restrict__ rc) {
  int t = blockIdx.x * 256 + threadIdx.x;
  if (t >= BQ * YQ) return;
  const float* pp = part + (size_t)t * 64;
  float M = -3.0e38f;
  #pragma unroll
  for (int h = 0; h < 32; ++h) M = fmaxf(M, pp[h * 2]);
  float Z = 0.f;
  #pragma unroll
  for (int h = 0; h < 32; ++h) Z += __expf(pp[h * 2] - M) * pp[h * 2 + 1];
  float iZ = 1.0f / Z;
  rs[t * 2] = M;
  rs[t * 2 + 1] = iZ;
  if (rc) {
    #pragma unroll
    for (int h = 0; h < 32; ++h)
      rc[(size_t)t * 32 + h] = __expf(pp[h * 2] - M) * iZ;
  }
}

// ---- fallback only: in-place S -> alpha (f32), vectorized ------------------
__global__ void k_alpha(float* __restrict__ a, const float* __restrict__ rs) {
  int r = blockIdx.x;
  float M = rs[r * 2], iZ = rs[r * 2 + 1];
  float* p = a + (size_t)r * SQ;
  int tid = threadIdx.x;
  #pragma unroll
  for (int i = 0; i < 2; ++i) {
    int e = (tid + i * 256) * 4;
    f32x4 v = ld4u(p + e);
    v.x = __expf(v.x - M) * iZ;
    v.y = __expf(v.y - M) * iZ;
    v.z = __expf(v.z - M) * iZ;
    v.w = __expf(v.w - M) * iZ;
    st4u(p + e, v);
  }
}

// ---- PV v2 fused: m = (P*corr) . x ; alpha f32 emitted during staging ------
// R13-exact 2D grid (R15's XCD remap was neutral-negative: xT is L3-resident).
__launch_bounds__(512, 4)
__global__ void k_pv2(const ushort* __restrict__ Pb, const float* __restrict__ rc,
                      const ushort* __restrict__ xT, float* __restrict__ mo,
                      float* __restrict__ aout) {
  __shared__ ushort sA[128 * 64];
  __shared__ ushort sB[256 * 64];
  const f32x4 fz4 = {0.f, 0.f, 0.f, 0.f};
  int tid = threadIdx.x;
  int d0 = blockIdx.x * 256;
  int y0 = blockIdx.y * 128;
  int b = blockIdx.z;
  int lane = tid & 63, wave = tid >> 6;
  int wm = wave >> 1;
  int wn = wave & 1;
  int lr = lane & 15, lg = lane >> 4;

  const ushort* Ap = Pb + ((size_t)b * YQ + y0) * SQ;
  const ushort* Bp = xT + ((size_t)b * DQ + d0) * SQ;

  f32x4 acc[2][8];
  #pragma unroll
  for (int i = 0; i < 2; ++i)
    #pragma unroll
    for (int j = 0; j < 8; ++j) acc[i][j] = fz4;

  for (int kc = 0; kc < SQ; kc += 64) {
    bool wr_alpha = ((kc >> 10) == (int)blockIdx.x);
    int hb = kc >> 6;
    // stage A: scale P by corr, repack bf16; optionally write alpha f32
    #pragma unroll
    for (int p = 0; p < 2; ++p) {
      int u = tid + p * 512;
      int r = u >> 3, c = u & 7;
      int y = y0 + r;
      ushort4 h0 = make_ushort4(0, 0, 0, 0), h1 = make_ushort4(0, 0, 0, 0);
      if (y < YQ) {
        size_t base = (size_t)r * SQ + kc + c * 8;
        s16x8 v = *(const s16x8*)(Ap + base);
        float corr = rc[((size_t)(b * YQ + y)) * 32 + hb];
        float pf[8];
        #pragma unroll
        for (int k2 = 0; k2 < 8; ++k2) pf[k2] = bf2f((ushort)v[k2]) * corr;
        if (wr_alpha) {
          float* ao = aout + ((size_t)b * YQ + y) * SQ + kc + c * 8;
          f32x4 w0 = {pf[0], pf[1], pf[2], pf[3]};
          f32x4 w1 = {pf[4], pf[5], pf[6], pf[7]};
          st4u(ao, w0);
          st4u(ao + 4, w1);
        }
        h0 = make_ushort4(f2bf(pf[0]), f2bf(pf[1]), f2bf(pf[2]), f2bf(pf[3]));
        h1 = make_ushort4(f2bf(pf[4]), f2bf(pf[5]), f2bf(pf[6]), f2bf(pf[7]));
      }
      int pofs = r * 64 + swz3(r, c) * 8;
      *(ushort4*)&sA[pofs] = h0;
      *(ushort4*)&sA[pofs + 4] = h1;
    }
    // stage B
    #pragma unroll
    for (int p = 0; p < 4; ++p) {
      int u = tid + p * 512;
      int r = u >> 3, c = u & 7;
      *(s16x8*)&sB[r * 64 + swz3(r, c) * 8] =
          *(const s16x8*)(Bp + (size_t)r * SQ + kc + c * 8);
    }
    __syncthreads();
    #pragma unroll
    for (int ks = 0; ks < 2; ++ks) {
      s16x8 af[2];
      #pragma unroll
      for (int i = 0; i < 2; ++i) {
        int row = wm * 32 + i * 16 + lr;
        af[i] = *(const s16x8*)&sA[row * 64 + swz3(row, ks * 4 + lg) * 8];
      }
      #pragma unroll
      for (int j = 0; j < 8; ++j) {
        int row = wn * 128 + j * 16 + lr;
        s16x8 bf = *(const s16x8*)&sB[row * 64 + swz3(row, ks * 4 + lg) * 8];
        acc[0][j] = mfma16(af[0], bf, acc[0][j]);
        acc[1][j] = mfma16(af[1], bf, acc[1][j]);
      }
    }
    __syncthreads();
  }

  float* out = mo + (size_t)b * YQ * DQ;
  #pragma unroll
  for (int i = 0; i < 2; ++i)
    #pragma unroll
    for (int q = 0; q < 4; ++q) {
      int r = y0 + wm * 32 + i * 16 + lg * 4 + q;
      if (r >= YQ) continue;
      #pragma unroll
      for (int j = 0; j < 8; ++j) {
        int col = d0 + wn * 128 + j * 16 + lr;
        out[(size_t)r * DQ + col] = acc[i][j][q];
      }
    }
}

// ---- PV fallback (small ws): m = alpha(f32,d_out) . x ----------------------
__launch_bounds__(256, 2)
__global__ void k_pv(const float* __restrict__ alpha, const ushort* __restrict__ xT,
                     float* __restrict__ mo) {
  __shared__ ushort sA[128 * LD];
  __shared__ ushort sB[128 * LD];
  const f32x4 fz4 = {0.f, 0.f, 0.f, 0.f};
  int tid = threadIdx.x;
  int d0 = blockIdx.x * 128;
  int y0 = blockIdx.y * 128;
  int b = blockIdx.z;
  const float* Ap = alpha + ((size_t)b * YQ + y0) * SQ;
  const ushort* Bp = xT + ((size_t)b * DQ + d0) * SQ;
  f32x4 acc[4][4];
  #pragma unroll
  for (int i = 0; i < 4; ++i)
    #pragma unroll
    for (int j = 0; j < 4; ++j) acc[i][j] = fz4;
  int lane = tid & 63, wave = tid >> 6;
  int wm = wave & 1, wn = wave >> 1;
  int lr = lane & 15, lg = lane >> 4;

  for (int kc = 0; kc < SQ; kc += 128) {
    __syncthreads();
    #pragma unroll
    for (int it = 0; it < 8; ++it) {
      int gi = tid + it * 256;
      int r = gi >> 4, g = gi & 15;
      int y = y0 + r;
      int pofs = r * LD + swz_chunk(r, g) * 8;
      ushort4 h0 = make_ushort4(0, 0, 0, 0), h1 = make_ushort4(0, 0, 0, 0);
      if (y < YQ) {
        f32x4 v0 = ld4u(Ap + (size_t)r * SQ + kc + g * 8);
        f32x4 v1 = ld4u(Ap + (size_t)r * SQ + kc + g * 8 + 4);
        h0 = make_ushort4(f2bf(v0.x), f2bf(v0.y), f2bf(v0.z), f2bf(v0.w));
        h1 = make_ushort4(f2bf(v1.x), f2bf(v1.y), f2bf(v1.z), f2bf(v1.w));
      }
      *(ushort4*)&sA[pofs] = h0;
      *(ushort4*)&sA[pofs + 4] = h1;
      *(s16x8*)&sB[pofs] = *(const s16x8*)(Bp + (size_t)r * SQ + kc + g * 8);
    }
    __syncthreads();
    #pragma unroll
    for (int ks = 0; ks < 4; ++ks) {
      s16x8 af[4], bfr[4];
      #pragma unroll
      for (int i = 0; i < 4; ++i) {
        int row = wm * 64 + i * 16 + lr;
        af[i] = *(const s16x8*)&sA[row * LD + swz_chunk(row, ks * 4 + lg) * 8];
      }
      #pragma unroll
      for (int i = 0; i < 4; ++i) {
        int row = wn * 64 + i * 16 + lr;
        bfr[i] = *(const s16x8*)&sB[row * LD + swz_chunk(row, ks * 4 + lg) * 8];
      }
      #pragma unroll
      for (int i = 0; i < 4; ++i)
        #pragma unroll
        for (int j = 0; j < 4; ++j)
          acc[i][j] = mfma16(af[i], bfr[j], acc[i][j]);
    }
  }
  float* out = mo + (size_t)b * YQ * DQ;
  int rb = wm * 64 + lg * 4;
  int cb_ = wn * 64 + lr;
  #pragma unroll
  for (int i = 0; i < 4; ++i)
    #pragma unroll
    for (int j = 0; j < 4; ++j) {
      int col = d0 + cb_ + j * 16;
      #pragma unroll
      for (int q = 0; q < 4; ++q) {
        int r = y0 + rb + i * 16 + q;
        if (r < YQ) out[(size_t)r * DQ + col] = acc[i][j][q];
      }
    }
}

// ------- y = m . final_w + b ; per-block loss partial (NO hot atomics) ------
__global__ void k_final(const float* __restrict__ m_in, const float* __restrict__ fw,
                        const float* __restrict__ fb, const float* __restrict__ tgt,
                        float* __restrict__ yo, float* __restrict__ part) {
  int y = blockIdx.x;
  int lane = threadIdx.x & 63;
  int b = threadIdx.x >> 6;
  const float* mp = m_in + ((size_t)b * YQ + y) * DQ;
  const float* wp = fw + (size_t)y * DQ;
  float s = 0.f;
  #pragma unroll
  for (int i = 0; i < 8; ++i) {
    int e = lane + i * 64;
    s += mp[e] * wp[e];
  }
  #pragma unroll
  for (int o = 32; o > 0; o >>= 1) s += __shfl_xor(s, o);
  __shared__ float pl[4];
  if (lane == 0) {
    float yv = s + fb[y];
    yo[(size_t)b * YQ + y] = yv;
    float t = tgt[(size_t)b * YQ + y];
    pl[b] = fmaxf(yv, 0.f) - yv * t + log1pf(__expf(-fabsf(yv)));
  }
  __syncthreads();
  if (threadIdx.x == 0)
    part[y] = (pl[0] + pl[1]) + (pl[2] + pl[3]);
}

// ------- reduce 8922 per-label partials -> mean loss ------------------------
__global__ void k_loss_fin(const float* __restrict__ part, float* __restrict__ out) {
  int tid = threadIdx.x;
  float s = 0.f;
  for (int i = tid; i < YQ; i += 256) s += part[i];
  #pragma unroll
  for (int o = 32; o > 0; o >>= 1) s += __shfl_xor(s, o);
  __shared__ float red[4];
  int lane = tid & 63, wave = tid >> 6;
  if (lane == 0) red[wave] = s;
  __syncthreads();
  if (tid == 0)
    out[0] = ((red[0] + red[1]) + (red[2] + red[3])) * (1.0f / (float)(BQ * YQ));
}

extern "C" void kernel_launch(void* const* d_in, const int* in_sizes, int n_in,
                              void* d_out, int out_size, void* d_ws, size_t ws_size,
                              hipStream_t stream) {
  const float* x      = (const float*)d_in[0];
  const float* target = (const float*)d_in[1];
  const int*   c2t    = (const int*)d_in[2];
  const float* embed  = (const float*)d_in[3];
  const float* cw     = (const float*)d_in[4];
  const float* cb     = (const float*)d_in[5];
  const float* fw     = (const float*)d_in[6];
  const float* fb     = (const float*)d_in[7];

  char* ws = (char*)d_ws;
  ushort* xb   = (ushort*)(ws);                 //  8,388,608 B
  ushort* xT   = (ushort*)(ws + 8388608);       //  8,388,608 B
  ushort* Wp   = (ushort*)(ws + 16777216);      //  1,179,648 B
  ushort* U    = (ushort*)(ws + 17956864);      //  9,175,040 B
  float* lpart = (float*)(ws + 27131904);       //  35,688 B
  float* part  = (float*)(ws + 27167744);       //  9,136,128 B  (35688*64*4)
  float* rst   = (float*)(ws + 36303872);       //    285,504 B  (35688*2*4)
  float* rc    = (float*)(ws + 36589568);       //  4,568,064 B  (35688*32*4)
  // rc ends at 41,157,632 (R10/R11 overlap bug fixed in R12).
  const size_t PB_OFF = 41157632;
  const size_t NEED_F = PB_OFF + (size_t)BQ * YQ * SQ * 2;   // ~187.4 MB
  bool fused = (ws_size >= NEED_F);
  ushort* Pb = fused ? (ushort*)(ws + PB_OFF) : (ushort*)0;

  float* out       = (float*)d_out;
  float* out_y     = out;                               // [B][Y]
  float* out_loss  = out + (size_t)BQ * YQ;             // scalar
  float* out_alpha = out + (size_t)BQ * YQ + 1;         // [B][Y][S]
  float* out_m     = out_alpha + (size_t)BQ * YQ * SQ;  // [B][Y][D]

  hipMemsetAsync(U, 0, (size_t)YPAD * DQ * 2, stream);

  k_prep_x<<<dim3(SQ / 64, DQ / 64, BQ), 256, 0, stream>>>(x, xb, xT);
  k_pack_w<<<dim3((KQ * DQ * EP + 255) / 256), 256, 0, stream>>>(cw, Wp);
  k_conv<<<dim3(4, (YQ + 3) / 4), 256, 0, stream>>>(c2t, embed, Wp, cb, U);
  k_scores<<<dim3(SQ / 128, (YQ + 127) / 128, BQ), 256, 0, stream>>>(
      U, xb, Pb, out_alpha, part);
  k_smfix<<<dim3((BQ * YQ + 255) / 256), 256, 0, stream>>>(part, rst,
                                                           fused ? rc : (float*)0);
  if (fused) {
    k_pv2<<<dim3(DQ / 256, (YQ + 127) / 128, BQ), 512, 0, stream>>>(
        Pb, rc, xT, out_m, out_alpha);
  } else {
    k_alpha<<<dim3(BQ * YQ), 256, 0, stream>>>(out_alpha, rst);
    k_pv<<<dim3(DQ / 128, (YQ + 127) / 128, BQ), 256, 0, stream>>>(
        out_alpha, xT, out_m);
  }
  k_final<<<dim3(YQ), 256, 0, stream>>>(out_m, fw, fb, target, out_y, lpart);
  k_loss_fin<<<1, 256, 0, stream>>>(lpart, out_loss);
}

// Round 17
// 806.041 us; speedup vs baseline: 1.0323x; 1.0008x over previous
//
#include <hip/hip_runtime.h>
#include <math.h>

#define BQ 4
#define SQ 2048
#define DQ 512
#define YQ 8922
#define TQ 32
#define EQ 100
#define EP 128      // E padded for MFMA K-steps
#define KQ 9
#define LD 128      // LDS leading dim (bf16) = 256B rows, 4-bit XOR swizzle
#define YPAD 8960

typedef float f32x4 __attribute__((ext_vector_type(4)));
typedef short s16x8 __attribute__((ext_vector_type(8)));

static __device__ __forceinline__ f32x4 mfma16(s16x8 a, s16x8 b, f32x4 c) {
  return __builtin_amdgcn_mfma_f32_16x16x32_bf16(a, b, c, 0, 0, 0);
}

static __device__ __forceinline__ ushort f2bf(float f) {
  union { float f; unsigned u; } v; v.f = f;
  unsigned r = (v.u + 0x7FFFu + ((v.u >> 16) & 1u)) >> 16;
  return (ushort)r;
}

static __device__ __forceinline__ float bf2f(ushort h) {
  union { unsigned u; float f; } v; v.u = ((unsigned)h) << 16; return v.f;
}

// unaligned (4B) 16-byte load/store
static __device__ __forceinline__ f32x4 ld4u(const float* p) {
  f32x4 v; __builtin_memcpy(&v, p, 16); return v;
}
static __device__ __forceinline__ void st4u(float* p, f32x4 v) {
  __builtin_memcpy(p, &v, 16);
}

// 4-bit XOR swizzle for 128-elem (256B) rows: 16 chunks (R3-proven)
static __device__ __forceinline__ int swz_chunk(int row, int chunk) {
  return chunk ^ (row & 15);
}
// 3-bit XOR swizzle for 64-elem (128B) rows: 8 chunks (pv2/R13-proven)
static __device__ __forceinline__ int swz3(int row, int chunk) {
  return chunk ^ (row & 7);
}

// ---- prep: x -> bf16 [B][S][D] and transposed [B][D][S]; vectorized --------
__global__ void k_prep_x(const float* __restrict__ x, ushort* __restrict__ xb,
                         ushort* __restrict__ xT) {
  __shared__ ushort sm[64][66];
  int b = blockIdx.z;
  int s0 = blockIdx.x * 64;
  int d0 = blockIdx.y * 64;
  int tid = threadIdx.x;
  int sr = tid >> 4;
  int c4 = (tid & 15) * 4;
  #pragma unroll
  for (int it = 0; it < 4; ++it) {
    int s = sr + it * 16;
    f32x4 v = *(const f32x4*)(x + ((size_t)b * SQ + s0 + s) * DQ + d0 + c4);
    ushort4 h = make_ushort4(f2bf(v.x), f2bf(v.y), f2bf(v.z), f2bf(v.w));
    *(ushort4*)(xb + ((size_t)b * SQ + s0 + s) * DQ + d0 + c4) = h;
    sm[s][c4] = h.x; sm[s][c4 + 1] = h.y; sm[s][c4 + 2] = h.z; sm[s][c4 + 3] = h.w;
  }
  __syncthreads();
  #pragma unroll
  for (int it = 0; it < 4; ++it) {
    int d = sr + it * 16;
    ushort4 h;
    h.x = sm[c4][d]; h.y = sm[c4 + 1][d]; h.z = sm[c4 + 2][d]; h.w = sm[c4 + 3][d];
    *(ushort4*)(xT + ((size_t)b * DQ + d0 + d) * SQ + s0 + c4) = h;
  }
}

// ---------------- pack conv_w [D][E][K] -> Wp bf16 [K][D][EP] (e>=100 -> 0) --
__global__ void k_pack_w(const float* __restrict__ cw, ushort* __restrict__ Wp) {
  int i = blockIdx.x * 256 + threadIdx.x;
  if (i >= KQ * DQ * EP) return;
  int e = i & (EP - 1);
  int d = (i >> 7) & (DQ - 1);
  int kk = i >> 16;
  float v = (e < EQ) ? cw[((size_t)d * EQ + e) * KQ + kk] : 0.f;
  Wp[i] = f2bf(v);
}

// ---- conv + maxpool + tanh + scale -> U bf16 [YQ][D] (R13-exact: 368us) ----
__launch_bounds__(256, 3)
__global__ void k_conv(const int* __restrict__ c2t, const float* __restrict__ embed,
                       const ushort* __restrict__ Wp, const float* __restrict__ cb,
                       ushort* __restrict__ U) {
  __shared__ ushort sA[4 * TQ * LD];   // 32 KB: 4 labels x 32 t x 128 e
  __shared__ ushort sB[128 * 64];      // 16 KB: 128 d x 64 e (one kk-half)
  const f32x4 fz4 = {0.f, 0.f, 0.f, 0.f};
  const s16x8 sz8 = {0, 0, 0, 0, 0, 0, 0, 0};
  int tid = threadIdx.x;
  int d0 = blockIdx.x * 128;
  int y0 = blockIdx.y * 4;
  int lane = tid & 63, wave = tid >> 6;
  int wm = wave & 1, wn = wave >> 1;
  int lr = lane & 15, lg = lane >> 4;

  // stage all title embeddings for 4 labels: [4*32] rows x [LD] bf16, swizzled
  {
    int row = tid >> 1;
    int half = tid & 1;
    int yl = row >> 5, t = row & 31;
    int y = y0 + yl;
    const float* src = 0;
    if (y < YQ) src = embed + (size_t)c2t[y * TQ + t] * EQ + half * 64;
    #pragma unroll
    for (int j = 0; j < 16; ++j) {
      int col = half * 64 + j * 4;
      f32x4 v = fz4;
      if (src != 0 && col + 4 <= EQ) v = *(const f32x4*)(src + j * 4);
      ushort4 h = make_ushort4(f2bf(v.x), f2bf(v.y), f2bf(v.z), f2bf(v.w));
      int pc = swz_chunk(row, col >> 3);
      *(ushort4*)&sA[row * LD + pc * 8 + (col & 7)] = h;
    }
  }

  // prologue: stage sB for step 0 (kk=0, e-half 0) via registers
  s16x8 breg[4];
  {
    const ushort* src = Wp + (size_t)d0 * EP;
    #pragma unroll
    for (int p = 0; p < 4; ++p) {
      int gi = tid + p * 256, r = gi >> 3, c = gi & 7;
      breg[p] = *(const s16x8*)(src + (size_t)r * EP + c * 8);
    }
    #pragma unroll
    for (int p = 0; p < 4; ++p) {
      int gi = tid + p * 256, r = gi >> 3, c = gi & 7;
      *(s16x8*)&sB[r * 64 + swz3(r, c) * 8] = breg[p];
    }
  }
  __syncthreads();

  f32x4 acc[4][4];
  #pragma unroll
  for (int i = 0; i < 4; ++i)
    #pragma unroll
    for (int j = 0; j < 4; ++j) acc[i][j] = fz4;

  for (int step = 0; step < 2 * KQ; ++step) {
    int kk = step >> 1, h = step & 1;
    // T14: issue next-step weight loads into regs BEFORE compute
    if (step + 1 < 2 * KQ) {
      int kk2 = (step + 1) >> 1, h2 = (step + 1) & 1;
      const ushort* src = Wp + ((size_t)kk2 * DQ + d0) * EP + h2 * 64;
      #pragma unroll
      for (int p = 0; p < 4; ++p) {
        int gi = tid + p * 256, r = gi >> 3, c = gi & 7;
        breg[p] = *(const s16x8*)(src + (size_t)r * EP + c * 8);
      }
    }
    #pragma unroll
    for (int e2 = 0; e2 < 2; ++e2) {
      int ee = h * 2 + e2;
      s16x8 af[4], bfr[4];
      #pragma unroll
      for (int i = 0; i < 4; ++i) {
        int rowm = wm * 64 + i * 16 + lr;
        int yl = rowm >> 5;
        int ts = (rowm & 31) + kk - 4;   // shifted time index
        s16x8 a = sz8;
        if ((unsigned)ts < (unsigned)TQ) {
          int row = yl * TQ + ts;
          a = *(const s16x8*)&sA[row * LD + swz_chunk(row, ee * 4 + lg) * 8];
        }
        af[i] = a;
      }
      #pragma unroll
      for (int i = 0; i < 4; ++i) {
        int row = wn * 64 + i * 16 + lr;
        bfr[i] = *(const s16x8*)&sB[row * 64 + swz3(row, e2 * 4 + lg) * 8];
      }
      #pragma unroll
      for (int i = 0; i < 4; ++i)
        #pragma unroll
        for (int j = 0; j < 4; ++j)
          acc[i][j] = mfma16(af[i], bfr[j], acc[i][j]);
    }
    __syncthreads();           // all waves done reading sB for this step
    if (step + 1 < 2 * KQ) {
      #pragma unroll
      for (int p = 0; p < 4; ++p) {
        int gi = tid + p * 256, r = gi >> 3, c = gi & 7;
        *(s16x8*)&sB[r * 64 + swz3(r, c) * 8] = breg[p];
      }
      __syncthreads();         // sB(step+1) visible
    }
  }

  // in-register epilogue: maxpool over t via in-lane fmax + shfl, tanh, scale
  const float scl = 0.04419417382415922f;   // 1/sqrt(D)
  #pragma unroll
  for (int L2 = 0; L2 < 2; ++L2) {
    int y = y0 + wm * 2 + L2;
    #pragma unroll
    for (int j = 0; j < 4; ++j) {
      float mx = -3.0e38f;
      #pragma unroll
      for (int ii = 0; ii < 2; ++ii)
        #pragma unroll
        for (int q = 0; q < 4; ++q)
          mx = fmaxf(mx, acc[L2 * 2 + ii][j][q]);
      mx = fmaxf(mx, __shfl_xor(mx, 16));
      mx = fmaxf(mx, __shfl_xor(mx, 32));
      if (lane < 16 && y < YQ) {
        int col = d0 + wn * 64 + j * 16 + lane;
        U[(size_t)y * DQ + col] = f2bf(tanhf(mx + cb[col]) * scl);
      }
    }
  }
}

// ---- scores: U . xb^T -> P=exp(S-Mloc) bf16 (fused) or raw S f32 (fallback)
//      + per-(row,64col) {max,sumexp} partials
// R17: K-chunk 64, sA/sB [128][64] swz3, LDS 32 KB -> 4 blocks/CU (R13 lever).
__launch_bounds__(256, 4)
__global__ void k_scores(const ushort* __restrict__ U, const ushort* __restrict__ xb,
                         ushort* __restrict__ Pb, float* __restrict__ sc,
                         float* __restrict__ part) {
  __shared__ ushort sA[128 * 64];   // 16 KB
  __shared__ ushort sB[128 * 64];   // 16 KB
  const f32x4 fz4 = {0.f, 0.f, 0.f, 0.f};
  int tid = threadIdx.x;
  int s0 = blockIdx.x * 128;
  int y0 = blockIdx.y * 128;
  int b = blockIdx.z;
  const ushort* Ap = U + (size_t)y0 * DQ;
  const ushort* Bp = xb + ((size_t)b * SQ + s0) * DQ;
  f32x4 acc[4][4];
  #pragma unroll
  for (int i = 0; i < 4; ++i)
    #pragma unroll
    for (int j = 0; j < 4; ++j) acc[i][j] = fz4;
  int lane = tid & 63, wave = tid >> 6;
  int wm = wave & 1, wn = wave >> 1;
  int lr = lane & 15, lg = lane >> 4;

  for (int kc = 0; kc < DQ; kc += 64) {
    __syncthreads();
    #pragma unroll
    for (int it = 0; it < 4; ++it) {
      int gi = tid + it * 256;
      int r = gi >> 3, c = gi & 7;
      int pofs = r * 64 + swz3(r, c) * 8;
      *(s16x8*)&sA[pofs] = *(const s16x8*)(Ap + (size_t)r * DQ + kc + c * 8);
      *(s16x8*)&sB[pofs] = *(const s16x8*)(Bp + (size_t)r * DQ + kc + c * 8);
    }
    __syncthreads();
    #pragma unroll
    for (int ks = 0; ks < 2; ++ks) {
      s16x8 af[4], bfr[4];
      #pragma unroll
      for (int i = 0; i < 4; ++i) {
        int row = wm * 64 + i * 16 + lr;
        af[i] = *(const s16x8*)&sA[row * 64 + swz3(row, ks * 4 + lg) * 8];
      }
      #pragma unroll
      for (int i = 0; i < 4; ++i) {
        int row = wn * 64 + i * 16 + lr;
        bfr[i] = *(const s16x8*)&sB[row * 64 + swz3(row, ks * 4 + lg) * 8];
      }
      #pragma unroll
      for (int i = 0; i < 4; ++i)
        #pragma unroll
        for (int j = 0; j < 4; ++j)
          acc[i][j] = mfma16(af[i], bfr[j], acc[i][j]);
    }
  }
  int rb = wm * 64 + lg * 4;
  int cb_ = wn * 64 + lr;
  int hb = blockIdx.x * 2 + wn;   // 64-col block index in [0,32)

  // row stats: per (i,q), max+sumexp over this wave's 64 cols
  float mxr[4][4];
  #pragma unroll
  for (int i = 0; i < 4; ++i)
    #pragma unroll
    for (int q = 0; q < 4; ++q) {
      float mx = fmaxf(fmaxf(acc[i][0][q], acc[i][1][q]),
                       fmaxf(acc[i][2][q], acc[i][3][q]));
      #pragma unroll
      for (int o = 1; o < 16; o <<= 1) mx = fmaxf(mx, __shfl_xor(mx, o));
      mxr[i][q] = mx;
      float se = 0.f;
      #pragma unroll
      for (int j = 0; j < 4; ++j) se += __expf(acc[i][j][q] - mx);
      #pragma unroll
      for (int o = 1; o < 16; o <<= 1) se += __shfl_xor(se, o);
      int r = y0 + rb + i * 16 + q;
      if (lr == 0 && r < YQ) {
        float* pp = part + ((size_t)(b * YQ + r) * 32 + hb) * 2;
        pp[0] = mx;
        pp[1] = se;
      }
    }

  if (Pb) {
    ushort* out = Pb + (size_t)b * YQ * SQ;
    #pragma unroll
    for (int i = 0; i < 4; ++i)
      #pragma unroll
      for (int j = 0; j < 4; ++j) {
        int col = s0 + cb_ + j * 16;
        #pragma unroll
        for (int q = 0; q < 4; ++q) {
          int r = y0 + rb + i * 16 + q;
          if (r < YQ)
            out[(size_t)r * SQ + col] = f2bf(__expf(acc[i][j][q] - mxr[i][q]));
        }
      }
  } else {
    float* out = sc + (size_t)b * YQ * SQ;
    #pragma unroll
    for (int i = 0; i < 4; ++i)
      #pragma unroll
      for (int j = 0; j < 4; ++j) {
        int col = s0 + cb_ + j * 16;
        #pragma unroll
        for (int q = 0; q < 4; ++q) {
          int r = y0 + rb + i * 16 + q;
          if (r < YQ) out[(size_t)r * SQ + col] = acc[i][j][q];
        }
      }
  }
}

// ---- merge 32 per-row partials -> rowstats {M,1/Z} + per-chunk corr --------
__global__ void k_smfix(const float* __restrict__ part, float* __restrict__ rs,
                        float* __restrict__ rc) {
  int t = blockIdx.x * 256 + threadIdx.x;
  if (t >= BQ * YQ) return;
  const float* pp = part + (size_t)t * 64;
  float M = -3.0e38f;
  #pragma unroll
  for (int h = 0; h < 32; ++h) M = fmaxf(M, pp[h * 2]);
  float Z = 0.f;
  #pragma unroll
  for (int h = 0; h < 32; ++h) Z += __expf(pp[h * 2] - M) * pp[h * 2 + 1];
  float iZ = 1.0f / Z;
  rs[t * 2] = M;
  rs[t * 2 + 1] = iZ;
  if (rc) {
    #pragma unroll
    for (int h = 0; h < 32; ++h)
      rc[(size_t)t * 32 + h] = __expf(pp[h * 2] - M) * iZ;
  }
}

// ---- fallback only: in-place S -> alpha (f32), vectorized ------------------
__global__ void k_alpha(float* __restrict__ a, const float* __restrict__ rs) {
  int r = blockIdx.x;
  float M = rs[r * 2], iZ = rs[r * 2 + 1];
  float* p = a + (size_t)r * SQ;
  int tid = threadIdx.x;
  #pragma unroll
  for (int i = 0; i < 2; ++i) {
    int e = (tid + i * 256) * 4;
    f32x4 v = ld4u(p + e);
    v.x = __expf(v.x - M) * iZ;
    v.y = __expf(v.y - M) * iZ;
    v.z = __expf(v.z - M) * iZ;
    v.w = __expf(v.w - M) * iZ;
    st4u(p + e, v);
  }
}

// ---- PV v2 fused: m = (P*corr) . x ; alpha f32 emitted during staging ------
// R13-exact 2D grid (R15's XCD remap was neutral-negative: xT is L3-resident).
__launch_bounds__(512, 4)
__global__ void k_pv2(const ushort* __restrict__ Pb, const float* __restrict__ rc,
                      const ushort* __restrict__ xT, float* __restrict__ mo,
                      float* __restrict__ aout) {
  __shared__ ushort sA[128 * 64];
  __shared__ ushort sB[256 * 64];
  const f32x4 fz4 = {0.f, 0.f, 0.f, 0.f};
  int tid = threadIdx.x;
  int d0 = blockIdx.x * 256;
  int y0 = blockIdx.y * 128;
  int b = blockIdx.z;
  int lane = tid & 63, wave = tid >> 6;
  int wm = wave >> 1;
  int wn = wave & 1;
  int lr = lane & 15, lg = lane >> 4;

  const ushort* Ap = Pb + ((size_t)b * YQ + y0) * SQ;
  const ushort* Bp = xT + ((size_t)b * DQ + d0) * SQ;

  f32x4 acc[2][8];
  #pragma unroll
  for (int i = 0; i < 2; ++i)
    #pragma unroll
    for (int j = 0; j < 8; ++j) acc[i][j] = fz4;

  for (int kc = 0; kc < SQ; kc += 64) {
    bool wr_alpha = ((kc >> 10) == (int)blockIdx.x);
    int hb = kc >> 6;
    // stage A: scale P by corr, repack bf16; optionally write alpha f32
    #pragma unroll
    for (int p = 0; p < 2; ++p) {
      int u = tid + p * 512;
      int r = u >> 3, c = u & 7;
      int y = y0 + r;
      ushort4 h0 = make_ushort4(0, 0, 0, 0), h1 = make_ushort4(0, 0, 0, 0);
      if (y < YQ) {
        size_t base = (size_t)r * SQ + kc + c * 8;
        s16x8 v = *(const s16x8*)(Ap + base);
        float corr = rc[((size_t)(b * YQ + y)) * 32 + hb];
        float pf[8];
        #pragma unroll
        for (int k2 = 0; k2 < 8; ++k2) pf[k2] = bf2f((ushort)v[k2]) * corr;
        if (wr_alpha) {
          float* ao = aout + ((size_t)b * YQ + y) * SQ + kc + c * 8;
          f32x4 w0 = {pf[0], pf[1], pf[2], pf[3]};
          f32x4 w1 = {pf[4], pf[5], pf[6], pf[7]};
          st4u(ao, w0);
          st4u(ao + 4, w1);
        }
        h0 = make_ushort4(f2bf(pf[0]), f2bf(pf[1]), f2bf(pf[2]), f2bf(pf[3]));
        h1 = make_ushort4(f2bf(pf[4]), f2bf(pf[5]), f2bf(pf[6]), f2bf(pf[7]));
      }
      int pofs = r * 64 + swz3(r, c) * 8;
      *(ushort4*)&sA[pofs] = h0;
      *(ushort4*)&sA[pofs + 4] = h1;
    }
    // stage B
    #pragma unroll
    for (int p = 0; p < 4; ++p) {
      int u = tid + p * 512;
      int r = u >> 3, c = u & 7;
      *(s16x8*)&sB[r * 64 + swz3(r, c) * 8] =
          *(const s16x8*)(Bp + (size_t)r * SQ + kc + c * 8);
    }
    __syncthreads();
    #pragma unroll
    for (int ks = 0; ks < 2; ++ks) {
      s16x8 af[2];
      #pragma unroll
      for (int i = 0; i < 2; ++i) {
        int row = wm * 32 + i * 16 + lr;
        af[i] = *(const s16x8*)&sA[row * 64 + swz3(row, ks * 4 + lg) * 8];
      }
      #pragma unroll
      for (int j = 0; j < 8; ++j) {
        int row = wn * 128 + j * 16 + lr;
        s16x8 bf = *(const s16x8*)&sB[row * 64 + swz3(row, ks * 4 + lg) * 8];
        acc[0][j] = mfma16(af[0], bf, acc[0][j]);
        acc[1][j] = mfma16(af[1], bf, acc[1][j]);
      }
    }
    __syncthreads();
  }

  float* out = mo + (size_t)b * YQ * DQ;
  #pragma unroll
  for (int i = 0; i < 2; ++i)
    #pragma unroll
    for (int q = 0; q < 4; ++q) {
      int r = y0 + wm * 32 + i * 16 + lg * 4 + q;
      if (r >= YQ) continue;
      #pragma unroll
      for (int j = 0; j < 8; ++j) {
        int col = d0 + wn * 128 + j * 16 + lr;
        out[(size_t)r * DQ + col] = acc[i][j][q];
      }
    }
}

// ---- PV fallback (small ws): m = alpha(f32,d_out) . x ----------------------
__launch_bounds__(256, 2)
__global__ void k_pv(const float* __restrict__ alpha, const ushort* __restrict__ xT,
                     float* __restrict__ mo) {
  __shared__ ushort sA[128 * LD];
  __shared__ ushort sB[128 * LD];
  const f32x4 fz4 = {0.f, 0.f, 0.f, 0.f};
  int tid = threadIdx.x;
  int d0 = blockIdx.x * 128;
  int y0 = blockIdx.y * 128;
  int b = blockIdx.z;
  const float* Ap = alpha + ((size_t)b * YQ + y0) * SQ;
  const ushort* Bp = xT + ((size_t)b * DQ + d0) * SQ;
  f32x4 acc[4][4];
  #pragma unroll
  for (int i = 0; i < 4; ++i)
    #pragma unroll
    for (int j = 0; j < 4; ++j) acc[i][j] = fz4;
  int lane = tid & 63, wave = tid >> 6;
  int wm = wave & 1, wn = wave >> 1;
  int lr = lane & 15, lg = lane >> 4;

  for (int kc = 0; kc < SQ; kc += 128) {
    __syncthreads();
    #pragma unroll
    for (int it = 0; it < 8; ++it) {
      int gi = tid + it * 256;
      int r = gi >> 4, g = gi & 15;
      int y = y0 + r;
      int pofs = r * LD + swz_chunk(r, g) * 8;
      ushort4 h0 = make_ushort4(0, 0, 0, 0), h1 = make_ushort4(0, 0, 0, 0);
      if (y < YQ) {
        f32x4 v0 = ld4u(Ap + (size_t)r * SQ + kc + g * 8);
        f32x4 v1 = ld4u(Ap + (size_t)r * SQ + kc + g * 8 + 4);
        h0 = make_ushort4(f2bf(v0.x), f2bf(v0.y), f2bf(v0.z), f2bf(v0.w));
        h1 = make_ushort4(f2bf(v1.x), f2bf(v1.y), f2bf(v1.z), f2bf(v1.w));
      }
      *(ushort4*)&sA[pofs] = h0;
      *(ushort4*)&sA[pofs + 4] = h1;
      *(s16x8*)&sB[pofs] = *(const s16x8*)(Bp + (size_t)r * SQ + kc + g * 8);
    }
    __syncthreads();
    #pragma unroll
    for (int ks = 0; ks < 4; ++ks) {
      s16x8 af[4], bfr[4];
      #pragma unroll
      for (int i = 0; i < 4; ++i) {
        int row = wm * 64 + i * 16 + lr;
        af[i] = *(const s16x8*)&sA[row * LD + swz_chunk(row, ks * 4 + lg) * 8];
      }
      #pragma unroll
      for (int i = 0; i < 4; ++i) {
        int row = wn * 64 + i * 16 + lr;
        bfr[i] = *(const s16x8*)&sB[row * LD + swz_chunk(row, ks * 4 + lg) * 8];
      }
      #pragma unroll
      for (int i = 0; i < 4; ++i)
        #pragma unroll
        for (int j = 0; j < 4; ++j)
          acc[i][j] = mfma16(af[i], bfr[j], acc[i][j]);
    }
  }
  float* out = mo + (size_t)b * YQ * DQ;
  int rb = wm * 64 + lg * 4;
  int cb_ = wn * 64 + lr;
  #pragma unroll
  for (int i = 0; i < 4; ++i)
    #pragma unroll
    for (int j = 0; j < 4; ++j) {
      int col = d0 + cb_ + j * 16;
      #pragma unroll
      for (int q = 0; q < 4; ++q) {
        int r = y0 + rb + i * 16 + q;
        if (r < YQ) out[(size_t)r * DQ + col] = acc[i][j][q];
      }
    }
}

// ------- y = m . final_w + b ; per-block loss partial (NO hot atomics) ------
__global__ void k_final(const float* __restrict__ m_in, const float* __restrict__ fw,
                        const float* __restrict__ fb, const float* __restrict__ tgt,
                        float* __restrict__ yo, float* __restrict__ part) {
  int y = blockIdx.x;
  int lane = threadIdx.x & 63;
  int b = threadIdx.x >> 6;
  const float* mp = m_in + ((size_t)b * YQ + y) * DQ;
  const float* wp = fw + (size_t)y * DQ;
  float s = 0.f;
  #pragma unroll
  for (int i = 0; i < 8; ++i) {
    int e = lane + i * 64;
    s += mp[e] * wp[e];
  }
  #pragma unroll
  for (int o = 32; o > 0; o >>= 1) s += __shfl_xor(s, o);
  __shared__ float pl[4];
  if (lane == 0) {
    float yv = s + fb[y];
    yo[(size_t)b * YQ + y] = yv;
    float t = tgt[(size_t)b * YQ + y];
    pl[b] = fmaxf(yv, 0.f) - yv * t + log1pf(__expf(-fabsf(yv)));
  }
  __syncthreads();
  if (threadIdx.x == 0)
    part[y] = (pl[0] + pl[1]) + (pl[2] + pl[3]);
}

// ------- reduce 8922 per-label partials -> mean loss ------------------------
__global__ void k_loss_fin(const float* __restrict__ part, float* __restrict__ out) {
  int tid = threadIdx.x;
  float s = 0.f;
  for (int i = tid; i < YQ; i += 256) s += part[i];
  #pragma unroll
  for (int o = 32; o > 0; o >>= 1) s += __shfl_xor(s, o);
  __shared__ float red[4];
  int lane = tid & 63, wave = tid >> 6;
  if (lane == 0) red[wave] = s;
  __syncthreads();
  if (tid == 0)
    out[0] = ((red[0] + red[1]) + (red[2] + red[3])) * (1.0f / (float)(BQ * YQ));
}

extern "C" void kernel_launch(void* const* d_in, const int* in_sizes, int n_in,
                              void* d_out, int out_size, void* d_ws, size_t ws_size,
                              hipStream_t stream) {
  const float* x      = (const float*)d_in[0];
  const float* target = (const float*)d_in[1];
  const int*   c2t    = (const int*)d_in[2];
  const float* embed  = (const float*)d_in[3];
  const float* cw     = (const float*)d_in[4];
  const float* cb     = (const float*)d_in[5];
  const float* fw     = (const float*)d_in[6];
  const float* fb     = (const float*)d_in[7];

  char* ws = (char*)d_ws;
  ushort* xb   = (ushort*)(ws);                 //  8,388,608 B
  ushort* xT   = (ushort*)(ws + 8388608);       //  8,388,608 B
  ushort* Wp   = (ushort*)(ws + 16777216);      //  1,179,648 B
  ushort* U    = (ushort*)(ws + 17956864);      //  9,175,040 B
  float* lpart = (float*)(ws + 27131904);       //  35,688 B
  float* part  = (float*)(ws + 27167744);       //  9,136,128 B  (35688*64*4)
  float* rst   = (float*)(ws + 36303872);       //    285,504 B  (35688*2*4)
  float* rc    = (float*)(ws + 36589568);       //  4,568,064 B  (35688*32*4)
  // rc ends at 41,157,632 (R10/R11 overlap bug fixed in R12).
  const size_t PB_OFF = 41157632;
  const size_t NEED_F = PB_OFF + (size_t)BQ * YQ * SQ * 2;   // ~187.4 MB
  bool fused = (ws_size >= NEED_F);
  ushort* Pb = fused ? (ushort*)(ws + PB_OFF) : (ushort*)0;

  float* out       = (float*)d_out;
  float* out_y     = out;                               // [B][Y]
  float* out_loss  = out + (size_t)BQ * YQ;             // scalar
  float* out_alpha = out + (size_t)BQ * YQ + 1;         // [B][Y][S]
  float* out_m     = out_alpha + (size_t)BQ * YQ * SQ;  // [B][Y][D]

  hipMemsetAsync(U, 0, (size_t)YPAD * DQ * 2, stream);

  k_prep_x<<<dim3(SQ / 64, DQ / 64, BQ), 256, 0, stream>>>(x, xb, xT);
  k_pack_w<<<dim3((KQ * DQ * EP + 255) / 256), 256, 0, stream>>>(cw, Wp);
  k_conv<<<dim3(4, (YQ + 3) / 4), 256, 0, stream>>>(c2t, embed, Wp, cb, U);
  k_scores<<<dim3(SQ / 128, (YQ + 127) / 128, BQ), 256, 0, stream>>>(
      U, xb, Pb, out_alpha, part);
  k_smfix<<<dim3((BQ * YQ + 255) / 256), 256, 0, stream>>>(part, rst,
                                                           fused ? rc : (float*)0);
  if (fused) {
    k_pv2<<<dim3(DQ / 256, (YQ + 127) / 128, BQ), 512, 0, stream>>>(
        Pb, rc, xT, out_m, out_alpha);
  } else {
    k_alpha<<<dim3(BQ * YQ), 256, 0, stream>>>(out_alpha, rst);
    k_pv<<<dim3(DQ / 128, (YQ + 127) / 128, BQ), 256, 0, stream>>>(
        out_alpha, xT, out_m);
  }
  k_final<<<dim3(YQ), 256, 0, stream>>>(out_m, fw, fb, target, out_y, lpart);
  k_loss_fin<<<1, 256, 0, stream>>>(lpart, out_loss);
}

// Round 18
// 800.979 us; speedup vs baseline: 1.0389x; 1.0063x over previous
//
#include <hip/hip_runtime.h>
#include <math.h>

#define BQ 4
#define SQ 2048
#define DQ 512
#define YQ 8922
#define TQ 32
#define EQ 100
#define EP 128      // E padded for MFMA K-steps
#define KQ 9
#define LD 128      // LDS leading dim (bf16) = 256B rows, 4-bit XOR swizzle
#define YPAD 8960

typedef float f32x4 __attribute__((ext_vector_type(4)));
typedef short s16x8 __attribute__((ext_vector_type(8)));

static __device__ __forceinline__ f32x4 mfma16(s16x8 a, s16x8 b, f32x4 c) {
  return __builtin_amdgcn_mfma_f32_16x16x32_bf16(a, b, c, 0, 0, 0);
}

static __device__ __forceinline__ ushort f2bf(float f) {
  union { float f; unsigned u; } v; v.f = f;
  unsigned r = (v.u + 0x7FFFu + ((v.u >> 16) & 1u)) >> 16;
  return (ushort)r;
}

static __device__ __forceinline__ float bf2f(ushort h) {
  union { unsigned u; float f; } v; v.u = ((unsigned)h) << 16; return v.f;
}

// unaligned (4B) 16-byte load/store
static __device__ __forceinline__ f32x4 ld4u(const float* p) {
  f32x4 v; __builtin_memcpy(&v, p, 16); return v;
}
static __device__ __forceinline__ void st4u(float* p, f32x4 v) {
  __builtin_memcpy(p, &v, 16);
}

// 4-bit XOR swizzle for 128-elem (256B) rows: 16 chunks (R3-proven)
static __device__ __forceinline__ int swz_chunk(int row, int chunk) {
  return chunk ^ (row & 15);
}
// 3-bit XOR swizzle for 64-elem (128B) rows: 8 chunks (pv2/R13-proven)
static __device__ __forceinline__ int swz3(int row, int chunk) {
  return chunk ^ (row & 7);
}

// ---- prep: x -> bf16 [B][S][D] and transposed [B][D][S]; vectorized --------
__global__ void k_prep_x(const float* __restrict__ x, ushort* __restrict__ xb,
                         ushort* __restrict__ xT) {
  __shared__ ushort sm[64][66];
  int b = blockIdx.z;
  int s0 = blockIdx.x * 64;
  int d0 = blockIdx.y * 64;
  int tid = threadIdx.x;
  int sr = tid >> 4;
  int c4 = (tid & 15) * 4;
  #pragma unroll
  for (int it = 0; it < 4; ++it) {
    int s = sr + it * 16;
    f32x4 v = *(const f32x4*)(x + ((size_t)b * SQ + s0 + s) * DQ + d0 + c4);
    ushort4 h = make_ushort4(f2bf(v.x), f2bf(v.y), f2bf(v.z), f2bf(v.w));
    *(ushort4*)(xb + ((size_t)b * SQ + s0 + s) * DQ + d0 + c4) = h;
    sm[s][c4] = h.x; sm[s][c4 + 1] = h.y; sm[s][c4 + 2] = h.z; sm[s][c4 + 3] = h.w;
  }
  __syncthreads();
  #pragma unroll
  for (int it = 0; it < 4; ++it) {
    int d = sr + it * 16;
    ushort4 h;
    h.x = sm[c4][d]; h.y = sm[c4 + 1][d]; h.z = sm[c4 + 2][d]; h.w = sm[c4 + 3][d];
    *(ushort4*)(xT + ((size_t)b * DQ + d0 + d) * SQ + s0 + c4) = h;
  }
}

// ---------------- pack conv_w [D][E][K] -> Wp bf16 [K][D][EP] (e>=100 -> 0) --
__global__ void k_pack_w(const float* __restrict__ cw, ushort* __restrict__ Wp) {
  int i = blockIdx.x * 256 + threadIdx.x;
  if (i >= KQ * DQ * EP) return;
  int e = i & (EP - 1);
  int d = (i >> 7) & (DQ - 1);
  int kk = i >> 16;
  float v = (e < EQ) ? cw[((size_t)d * EQ + e) * KQ + kk] : 0.f;
  Wp[i] = f2bf(v);
}

// ---- conv + maxpool + tanh + scale -> U bf16 [YQ][D] (R13-exact: 368us) ----
__launch_bounds__(256, 3)
__global__ void k_conv(const int* __restrict__ c2t, const float* __restrict__ embed,
                       const ushort* __restrict__ Wp, const float* __restrict__ cb,
                       ushort* __restrict__ U) {
  __shared__ ushort sA[4 * TQ * LD];   // 32 KB: 4 labels x 32 t x 128 e
  __shared__ ushort sB[128 * 64];      // 16 KB: 128 d x 64 e (one kk-half)
  const f32x4 fz4 = {0.f, 0.f, 0.f, 0.f};
  const s16x8 sz8 = {0, 0, 0, 0, 0, 0, 0, 0};
  int tid = threadIdx.x;
  int d0 = blockIdx.x * 128;
  int y0 = blockIdx.y * 4;
  int lane = tid & 63, wave = tid >> 6;
  int wm = wave & 1, wn = wave >> 1;
  int lr = lane & 15, lg = lane >> 4;

  // stage all title embeddings for 4 labels: [4*32] rows x [LD] bf16, swizzled
  {
    int row = tid >> 1;
    int half = tid & 1;
    int yl = row >> 5, t = row & 31;
    int y = y0 + yl;
    const float* src = 0;
    if (y < YQ) src = embed + (size_t)c2t[y * TQ + t] * EQ + half * 64;
    #pragma unroll
    for (int j = 0; j < 16; ++j) {
      int col = half * 64 + j * 4;
      f32x4 v = fz4;
      if (src != 0 && col + 4 <= EQ) v = *(const f32x4*)(src + j * 4);
      ushort4 h = make_ushort4(f2bf(v.x), f2bf(v.y), f2bf(v.z), f2bf(v.w));
      int pc = swz_chunk(row, col >> 3);
      *(ushort4*)&sA[row * LD + pc * 8 + (col & 7)] = h;
    }
  }

  // prologue: stage sB for step 0 (kk=0, e-half 0) via registers
  s16x8 breg[4];
  {
    const ushort* src = Wp + (size_t)d0 * EP;
    #pragma unroll
    for (int p = 0; p < 4; ++p) {
      int gi = tid + p * 256, r = gi >> 3, c = gi & 7;
      breg[p] = *(const s16x8*)(src + (size_t)r * EP + c * 8);
    }
    #pragma unroll
    for (int p = 0; p < 4; ++p) {
      int gi = tid + p * 256, r = gi >> 3, c = gi & 7;
      *(s16x8*)&sB[r * 64 + swz3(r, c) * 8] = breg[p];
    }
  }
  __syncthreads();

  f32x4 acc[4][4];
  #pragma unroll
  for (int i = 0; i < 4; ++i)
    #pragma unroll
    for (int j = 0; j < 4; ++j) acc[i][j] = fz4;

  for (int step = 0; step < 2 * KQ; ++step) {
    int kk = step >> 1, h = step & 1;
    // T14: issue next-step weight loads into regs BEFORE compute
    if (step + 1 < 2 * KQ) {
      int kk2 = (step + 1) >> 1, h2 = (step + 1) & 1;
      const ushort* src = Wp + ((size_t)kk2 * DQ + d0) * EP + h2 * 64;
      #pragma unroll
      for (int p = 0; p < 4; ++p) {
        int gi = tid + p * 256, r = gi >> 3, c = gi & 7;
        breg[p] = *(const s16x8*)(src + (size_t)r * EP + c * 8);
      }
    }
    #pragma unroll
    for (int e2 = 0; e2 < 2; ++e2) {
      int ee = h * 2 + e2;
      s16x8 af[4], bfr[4];
      #pragma unroll
      for (int i = 0; i < 4; ++i) {
        int rowm = wm * 64 + i * 16 + lr;
        int yl = rowm >> 5;
        int ts = (rowm & 31) + kk - 4;   // shifted time index
        s16x8 a = sz8;
        if ((unsigned)ts < (unsigned)TQ) {
          int row = yl * TQ + ts;
          a = *(const s16x8*)&sA[row * LD + swz_chunk(row, ee * 4 + lg) * 8];
        }
        af[i] = a;
      }
      #pragma unroll
      for (int i = 0; i < 4; ++i) {
        int row = wn * 64 + i * 16 + lr;
        bfr[i] = *(const s16x8*)&sB[row * 64 + swz3(row, e2 * 4 + lg) * 8];
      }
      #pragma unroll
      for (int i = 0; i < 4; ++i)
        #pragma unroll
        for (int j = 0; j < 4; ++j)
          acc[i][j] = mfma16(af[i], bfr[j], acc[i][j]);
    }
    __syncthreads();           // all waves done reading sB for this step
    if (step + 1 < 2 * KQ) {
      #pragma unroll
      for (int p = 0; p < 4; ++p) {
        int gi = tid + p * 256, r = gi >> 3, c = gi & 7;
        *(s16x8*)&sB[r * 64 + swz3(r, c) * 8] = breg[p];
      }
      __syncthreads();         // sB(step+1) visible
    }
  }

  // in-register epilogue: maxpool over t via in-lane fmax + shfl, tanh, scale
  const float scl = 0.04419417382415922f;   // 1/sqrt(D)
  #pragma unroll
  for (int L2 = 0; L2 < 2; ++L2) {
    int y = y0 + wm * 2 + L2;
    #pragma unroll
    for (int j = 0; j < 4; ++j) {
      float mx = -3.0e38f;
      #pragma unroll
      for (int ii = 0; ii < 2; ++ii)
        #pragma unroll
        for (int q = 0; q < 4; ++q)
          mx = fmaxf(mx, acc[L2 * 2 + ii][j][q]);
      mx = fmaxf(mx, __shfl_xor(mx, 16));
      mx = fmaxf(mx, __shfl_xor(mx, 32));
      if (lane < 16 && y < YQ) {
        int col = d0 + wn * 64 + j * 16 + lane;
        U[(size_t)y * DQ + col] = f2bf(tanhf(mx + cb[col]) * scl);
      }
    }
  }
}

// ---- scores: U . xb^T -> P=exp(S-Mloc) bf16 (fused) or raw S f32 (fallback)
//      + per-(row,64col) {max,sumexp} partials (R17 config, 32 KB LDS) -------
__launch_bounds__(256, 4)
__global__ void k_scores(const ushort* __restrict__ U, const ushort* __restrict__ xb,
                         ushort* __restrict__ Pb, float* __restrict__ sc,
                         float* __restrict__ part) {
  __shared__ ushort sA[128 * 64];   // 16 KB
  __shared__ ushort sB[128 * 64];   // 16 KB
  const f32x4 fz4 = {0.f, 0.f, 0.f, 0.f};
  int tid = threadIdx.x;
  int s0 = blockIdx.x * 128;
  int y0 = blockIdx.y * 128;
  int b = blockIdx.z;
  const ushort* Ap = U + (size_t)y0 * DQ;
  const ushort* Bp = xb + ((size_t)b * SQ + s0) * DQ;
  f32x4 acc[4][4];
  #pragma unroll
  for (int i = 0; i < 4; ++i)
    #pragma unroll
    for (int j = 0; j < 4; ++j) acc[i][j] = fz4;
  int lane = tid & 63, wave = tid >> 6;
  int wm = wave & 1, wn = wave >> 1;
  int lr = lane & 15, lg = lane >> 4;

  for (int kc = 0; kc < DQ; kc += 64) {
    __syncthreads();
    #pragma unroll
    for (int it = 0; it < 4; ++it) {
      int gi = tid + it * 256;
      int r = gi >> 3, c = gi & 7;
      int pofs = r * 64 + swz3(r, c) * 8;
      *(s16x8*)&sA[pofs] = *(const s16x8*)(Ap + (size_t)r * DQ + kc + c * 8);
      *(s16x8*)&sB[pofs] = *(const s16x8*)(Bp + (size_t)r * DQ + kc + c * 8);
    }
    __syncthreads();
    #pragma unroll
    for (int ks = 0; ks < 2; ++ks) {
      s16x8 af[4], bfr[4];
      #pragma unroll
      for (int i = 0; i < 4; ++i) {
        int row = wm * 64 + i * 16 + lr;
        af[i] = *(const s16x8*)&sA[row * 64 + swz3(row, ks * 4 + lg) * 8];
      }
      #pragma unroll
      for (int i = 0; i < 4; ++i) {
        int row = wn * 64 + i * 16 + lr;
        bfr[i] = *(const s16x8*)&sB[row * 64 + swz3(row, ks * 4 + lg) * 8];
      }
      #pragma unroll
      for (int i = 0; i < 4; ++i)
        #pragma unroll
        for (int j = 0; j < 4; ++j)
          acc[i][j] = mfma16(af[i], bfr[j], acc[i][j]);
    }
  }
  int rb = wm * 64 + lg * 4;
  int cb_ = wn * 64 + lr;
  int hb = blockIdx.x * 2 + wn;   // 64-col block index in [0,32)

  // row stats: per (i,q), max+sumexp over this wave's 64 cols
  float mxr[4][4];
  #pragma unroll
  for (int i = 0; i < 4; ++i)
    #pragma unroll
    for (int q = 0; q < 4; ++q) {
      float mx = fmaxf(fmaxf(acc[i][0][q], acc[i][1][q]),
                       fmaxf(acc[i][2][q], acc[i][3][q]));
      #pragma unroll
      for (int o = 1; o < 16; o <<= 1) mx = fmaxf(mx, __shfl_xor(mx, o));
      mxr[i][q] = mx;
      float se = 0.f;
      #pragma unroll
      for (int j = 0; j < 4; ++j) se += __expf(acc[i][j][q] - mx);
      #pragma unroll
      for (int o = 1; o < 16; o <<= 1) se += __shfl_xor(se, o);
      int r = y0 + rb + i * 16 + q;
      if (lr == 0 && r < YQ) {
        float* pp = part + ((size_t)(b * YQ + r) * 32 + hb) * 2;
        pp[0] = mx;
        pp[1] = se;
      }
    }

  if (Pb) {
    ushort* out = Pb + (size_t)b * YQ * SQ;
    #pragma unroll
    for (int i = 0; i < 4; ++i)
      #pragma unroll
      for (int j = 0; j < 4; ++j) {
        int col = s0 + cb_ + j * 16;
        #pragma unroll
        for (int q = 0; q < 4; ++q) {
          int r = y0 + rb + i * 16 + q;
          if (r < YQ)
            out[(size_t)r * SQ + col] = f2bf(__expf(acc[i][j][q] - mxr[i][q]));
        }
      }
  } else {
    float* out = sc + (size_t)b * YQ * SQ;
    #pragma unroll
    for (int i = 0; i < 4; ++i)
      #pragma unroll
      for (int j = 0; j < 4; ++j) {
        int col = s0 + cb_ + j * 16;
        #pragma unroll
        for (int q = 0; q < 4; ++q) {
          int r = y0 + rb + i * 16 + q;
          if (r < YQ) out[(size_t)r * SQ + col] = acc[i][j][q];
        }
      }
  }
}

// ---- merge 32 per-row partials -> rowstats {M,1/Z} + per-chunk corr --------
__global__ void k_smfix(const float* __restrict__ part, float* __restrict__ rs,
                        float* __restrict__ rc) {
  int t = blockIdx.x * 256 + threadIdx.x;
  if (t >= BQ * YQ) return;
  const float* pp = part + (size_t)t * 64;
  float M = -3.0e38f;
  #pragma unroll
  for (int h = 0; h < 32; ++h) M = fmaxf(M, pp[h * 2]);
  float Z = 0.f;
  #pragma unroll
  for (int h = 0; h < 32; ++h) Z += __expf(pp[h * 2] - M) * pp[h * 2 + 1];
  float iZ = 1.0f / Z;
  rs[t * 2] = M;
  rs[t * 2 + 1] = iZ;
  if (rc) {
    #pragma unroll
    for (int h = 0; h < 32; ++h)
      rc[(size_t)t * 32 + h] = __expf(pp[h * 2] - M) * iZ;
  }
}

// ---- fallback only: in-place S -> alpha (f32), vectorized ------------------
__global__ void k_alpha(float* __restrict__ a, const float* __restrict__ rs) {
  int r = blockIdx.x;
  float M = rs[r * 2], iZ = rs[r * 2 + 1];
  float* p = a + (size_t)r * SQ;
  int tid = threadIdx.x;
  #pragma unroll
  for (int i = 0; i < 2; ++i) {
    int e = (tid + i * 256) * 4;
    f32x4 v = ld4u(p + e);
    v.x = __expf(v.x - M) * iZ;
    v.y = __expf(v.y - M) * iZ;
    v.z = __expf(v.z - M) * iZ;
    v.w = __expf(v.w - M) * iZ;
    st4u(p + e, v);
  }
}

// ---- PV v2 fused: m = (P*corr) . x ; alpha f32 emitted during staging ------
// R18: epilogue additionally computes partial dots m[r].fw[r] over this
// block's 256-col half-panels -> fpart[(b*YQ+r)*4 + d0i*2 + wn] (k_final fused)
__launch_bounds__(512, 4)
__global__ void k_pv2(const ushort* __restrict__ Pb, const float* __restrict__ rc,
                      const ushort* __restrict__ xT, const float* __restrict__ fw,
                      float* __restrict__ mo, float* __restrict__ aout,
                      float* __restrict__ fpart) {
  __shared__ ushort sA[128 * 64];
  __shared__ ushort sB[256 * 64];
  const f32x4 fz4 = {0.f, 0.f, 0.f, 0.f};
  int tid = threadIdx.x;
  int d0 = blockIdx.x * 256;
  int y0 = blockIdx.y * 128;
  int b = blockIdx.z;
  int lane = tid & 63, wave = tid >> 6;
  int wm = wave >> 1;
  int wn = wave & 1;
  int lr = lane & 15, lg = lane >> 4;

  const ushort* Ap = Pb + ((size_t)b * YQ + y0) * SQ;
  const ushort* Bp = xT + ((size_t)b * DQ + d0) * SQ;

  f32x4 acc[2][8];
  #pragma unroll
  for (int i = 0; i < 2; ++i)
    #pragma unroll
    for (int j = 0; j < 8; ++j) acc[i][j] = fz4;

  for (int kc = 0; kc < SQ; kc += 64) {
    bool wr_alpha = ((kc >> 10) == (int)blockIdx.x);
    int hb = kc >> 6;
    // stage A: scale P by corr, repack bf16; optionally write alpha f32
    #pragma unroll
    for (int p = 0; p < 2; ++p) {
      int u = tid + p * 512;
      int r = u >> 3, c = u & 7;
      int y = y0 + r;
      ushort4 h0 = make_ushort4(0, 0, 0, 0), h1 = make_ushort4(0, 0, 0, 0);
      if (y < YQ) {
        size_t base = (size_t)r * SQ + kc + c * 8;
        s16x8 v = *(const s16x8*)(Ap + base);
        float corr = rc[((size_t)(b * YQ + y)) * 32 + hb];
        float pf[8];
        #pragma unroll
        for (int k2 = 0; k2 < 8; ++k2) pf[k2] = bf2f((ushort)v[k2]) * corr;
        if (wr_alpha) {
          float* ao = aout + ((size_t)b * YQ + y) * SQ + kc + c * 8;
          f32x4 w0 = {pf[0], pf[1], pf[2], pf[3]};
          f32x4 w1 = {pf[4], pf[5], pf[6], pf[7]};
          st4u(ao, w0);
          st4u(ao + 4, w1);
        }
        h0 = make_ushort4(f2bf(pf[0]), f2bf(pf[1]), f2bf(pf[2]), f2bf(pf[3]));
        h1 = make_ushort4(f2bf(pf[4]), f2bf(pf[5]), f2bf(pf[6]), f2bf(pf[7]));
      }
      int pofs = r * 64 + swz3(r, c) * 8;
      *(ushort4*)&sA[pofs] = h0;
      *(ushort4*)&sA[pofs + 4] = h1;
    }
    // stage B
    #pragma unroll
    for (int p = 0; p < 4; ++p) {
      int u = tid + p * 512;
      int r = u >> 3, c = u & 7;
      *(s16x8*)&sB[r * 64 + swz3(r, c) * 8] =
          *(const s16x8*)(Bp + (size_t)r * SQ + kc + c * 8);
    }
    __syncthreads();
    #pragma unroll
    for (int ks = 0; ks < 2; ++ks) {
      s16x8 af[2];
      #pragma unroll
      for (int i = 0; i < 2; ++i) {
        int row = wm * 32 + i * 16 + lr;
        af[i] = *(const s16x8*)&sA[row * 64 + swz3(row, ks * 4 + lg) * 8];
      }
      #pragma unroll
      for (int j = 0; j < 8; ++j) {
        int row = wn * 128 + j * 16 + lr;
        s16x8 bf = *(const s16x8*)&sB[row * 64 + swz3(row, ks * 4 + lg) * 8];
        acc[0][j] = mfma16(af[0], bf, acc[0][j]);
        acc[1][j] = mfma16(af[1], bf, acc[1][j]);
      }
    }
    __syncthreads();
  }

  float* out = mo + (size_t)b * YQ * DQ;
  #pragma unroll
  for (int i = 0; i < 2; ++i)
    #pragma unroll
    for (int q = 0; q < 4; ++q) {
      int r = y0 + wm * 32 + i * 16 + lg * 4 + q;
      if (r >= YQ) continue;
      float s = 0.f;
      #pragma unroll
      for (int j = 0; j < 8; ++j) {
        int col = d0 + wn * 128 + j * 16 + lr;
        float mv = acc[i][j][q];
        out[(size_t)r * DQ + col] = mv;
        s += mv * fw[(size_t)r * DQ + col];
      }
      // reduce partial dot over the 16 lr lanes (shfl stays in-group, o<16)
      #pragma unroll
      for (int o = 1; o < 16; o <<= 1) s += __shfl_xor(s, o);
      if (lr == 0)
        fpart[((size_t)(b * YQ + r)) * 4 + (int)blockIdx.x * 2 + wn] = s;
    }
}

// ---- PV fallback (small ws): m = alpha(f32,d_out) . x ----------------------
__launch_bounds__(256, 2)
__global__ void k_pv(const float* __restrict__ alpha, const ushort* __restrict__ xT,
                     float* __restrict__ mo) {
  __shared__ ushort sA[128 * LD];
  __shared__ ushort sB[128 * LD];
  const f32x4 fz4 = {0.f, 0.f, 0.f, 0.f};
  int tid = threadIdx.x;
  int d0 = blockIdx.x * 128;
  int y0 = blockIdx.y * 128;
  int b = blockIdx.z;
  const float* Ap = alpha + ((size_t)b * YQ + y0) * SQ;
  const ushort* Bp = xT + ((size_t)b * DQ + d0) * SQ;
  f32x4 acc[4][4];
  #pragma unroll
  for (int i = 0; i < 4; ++i)
    #pragma unroll
    for (int j = 0; j < 4; ++j) acc[i][j] = fz4;
  int lane = tid & 63, wave = tid >> 6;
  int wm = wave & 1, wn = wave >> 1;
  int lr = lane & 15, lg = lane >> 4;

  for (int kc = 0; kc < SQ; kc += 128) {
    __syncthreads();
    #pragma unroll
    for (int it = 0; it < 8; ++it) {
      int gi = tid + it * 256;
      int r = gi >> 4, g = gi & 15;
      int y = y0 + r;
      int pofs = r * LD + swz_chunk(r, g) * 8;
      ushort4 h0 = make_ushort4(0, 0, 0, 0), h1 = make_ushort4(0, 0, 0, 0);
      if (y < YQ) {
        f32x4 v0 = ld4u(Ap + (size_t)r * SQ + kc + g * 8);
        f32x4 v1 = ld4u(Ap + (size_t)r * SQ + kc + g * 8 + 4);
        h0 = make_ushort4(f2bf(v0.x), f2bf(v0.y), f2bf(v0.z), f2bf(v0.w));
        h1 = make_ushort4(f2bf(v1.x), f2bf(v1.y), f2bf(v1.z), f2bf(v1.w));
      }
      *(ushort4*)&sA[pofs] = h0;
      *(ushort4*)&sA[pofs + 4] = h1;
      *(s16x8*)&sB[pofs] = *(const s16x8*)(Bp + (size_t)r * SQ + kc + g * 8);
    }
    __syncthreads();
    #pragma unroll
    for (int ks = 0; ks < 4; ++ks) {
      s16x8 af[4], bfr[4];
      #pragma unroll
      for (int i = 0; i < 4; ++i) {
        int row = wm * 64 + i * 16 + lr;
        af[i] = *(const s16x8*)&sA[row * LD + swz_chunk(row, ks * 4 + lg) * 8];
      }
      #pragma unroll
      for (int i = 0; i < 4; ++i) {
        int row = wn * 64 + i * 16 + lr;
        bfr[i] = *(const s16x8*)&sB[row * LD + swz_chunk(row, ks * 4 + lg) * 8];
      }
      #pragma unroll
      for (int i = 0; i < 4; ++i)
        #pragma unroll
        for (int j = 0; j < 4; ++j)
          acc[i][j] = mfma16(af[i], bfr[j], acc[i][j]);
    }
  }
  float* out = mo + (size_t)b * YQ * DQ;
  int rb = wm * 64 + lg * 4;
  int cb_ = wn * 64 + lr;
  #pragma unroll
  for (int i = 0; i < 4; ++i)
    #pragma unroll
    for (int j = 0; j < 4; ++j) {
      int col = d0 + cb_ + j * 16;
      #pragma unroll
      for (int q = 0; q < 4; ++q) {
        int r = y0 + rb + i * 16 + q;
        if (r < YQ) out[(size_t)r * DQ + col] = acc[i][j][q];
      }
    }
}

// ------- fused-path finalizer: 4 partials -> y, BCE term; per-block sum -----
__global__ void k_final2(const float* __restrict__ fpart, const float* __restrict__ fb,
                         const float* __restrict__ tgt, float* __restrict__ yo,
                         float* __restrict__ lpart) {
  int t = blockIdx.x * 256 + threadIdx.x;
  float l = 0.f;
  if (t < BQ * YQ) {
    int b = t / YQ, y = t - b * YQ;
    const float* fp = fpart + (size_t)t * 4;
    float yv = (fp[0] + fp[1]) + (fp[2] + fp[3]) + fb[y];
    yo[t] = yv;                 // t == b*YQ + y
    float tg = tgt[t];
    l = fmaxf(yv, 0.f) - yv * tg + log1pf(__expf(-fabsf(yv)));
  }
  int lane = threadIdx.x & 63, wave = threadIdx.x >> 6;
  #pragma unroll
  for (int o = 32; o > 0; o >>= 1) l += __shfl_xor(l, o);
  __shared__ float red[4];
  if (lane == 0) red[wave] = l;
  __syncthreads();
  if (threadIdx.x == 0)
    lpart[blockIdx.x] = (red[0] + red[1]) + (red[2] + red[3]);
}

// ------- fallback finalizer: y = m . final_w + b ; per-label loss partial ---
__global__ void k_final(const float* __restrict__ m_in, const float* __restrict__ fw,
                        const float* __restrict__ fb, const float* __restrict__ tgt,
                        float* __restrict__ yo, float* __restrict__ part) {
  int y = blockIdx.x;
  int lane = threadIdx.x & 63;
  int b = threadIdx.x >> 6;
  const float* mp = m_in + ((size_t)b * YQ + y) * DQ;
  const float* wp = fw + (size_t)y * DQ;
  float s = 0.f;
  #pragma unroll
  for (int i = 0; i < 8; ++i) {
    int e = lane + i * 64;
    s += mp[e] * wp[e];
  }
  #pragma unroll
  for (int o = 32; o > 0; o >>= 1) s += __shfl_xor(s, o);
  __shared__ float pl[4];
  if (lane == 0) {
    float yv = s + fb[y];
    yo[(size_t)b * YQ + y] = yv;
    float t = tgt[(size_t)b * YQ + y];
    pl[b] = fmaxf(yv, 0.f) - yv * t + log1pf(__expf(-fabsf(yv)));
  }
  __syncthreads();
  if (threadIdx.x == 0)
    part[y] = (pl[0] + pl[1]) + (pl[2] + pl[3]);
}

// ------- reduce n loss partials -> mean loss --------------------------------
__global__ void k_loss_fin(const float* __restrict__ part, int n,
                           float* __restrict__ out) {
  int tid = threadIdx.x;
  float s = 0.f;
  for (int i = tid; i < n; i += 256) s += part[i];
  #pragma unroll
  for (int o = 32; o > 0; o >>= 1) s += __shfl_xor(s, o);
  __shared__ float red[4];
  int lane = tid & 63, wave = tid >> 6;
  if (lane == 0) red[wave] = s;
  __syncthreads();
  if (tid == 0)
    out[0] = ((red[0] + red[1]) + (red[2] + red[3])) * (1.0f / (float)(BQ * YQ));
}

extern "C" void kernel_launch(void* const* d_in, const int* in_sizes, int n_in,
                              void* d_out, int out_size, void* d_ws, size_t ws_size,
                              hipStream_t stream) {
  const float* x      = (const float*)d_in[0];
  const float* target = (const float*)d_in[1];
  const int*   c2t    = (const int*)d_in[2];
  const float* embed  = (const float*)d_in[3];
  const float* cw     = (const float*)d_in[4];
  const float* cb     = (const float*)d_in[5];
  const float* fw     = (const float*)d_in[6];
  const float* fb     = (const float*)d_in[7];

  char* ws = (char*)d_ws;
  ushort* xb   = (ushort*)(ws);                 //  8,388,608 B
  ushort* xT   = (ushort*)(ws + 8388608);       //  8,388,608 B
  ushort* Wp   = (ushort*)(ws + 16777216);      //  1,179,648 B
  ushort* U    = (ushort*)(ws + 17956864);      //  9,175,040 B
  float* lpart = (float*)(ws + 27131904);       //  35,688 B
  float* part  = (float*)(ws + 27167744);       //  9,136,128 B  (35688*64*4)
  float* rst   = (float*)(ws + 36303872);       //    285,504 B  (35688*2*4)
  float* rc    = (float*)(ws + 36589568);       //  4,568,064 B  (35688*32*4)
  // rc ends at 36,589,568 + 4,568,064 = 41,157,632 (R12-verified layout).
  const size_t PB_OFF = 41157632;
  const size_t PB_BYTES = (size_t)BQ * YQ * SQ * 2;          // 146,227,200
  const size_t FP_OFF = PB_OFF + PB_BYTES;                   // 187,384,832
  const size_t FP_BYTES = (size_t)BQ * YQ * 4 * 4;           // 571,008
  const size_t NEED_F = FP_OFF + FP_BYTES;                   // ~188.0 MB
  bool fused = (ws_size >= NEED_F);
  ushort* Pb = fused ? (ushort*)(ws + PB_OFF) : (ushort*)0;
  float* fpart = (float*)(ws + FP_OFF);

  float* out       = (float*)d_out;
  float* out_y     = out;                               // [B][Y]
  float* out_loss  = out + (size_t)BQ * YQ;             // scalar
  float* out_alpha = out + (size_t)BQ * YQ + 1;         // [B][Y][S]
  float* out_m     = out_alpha + (size_t)BQ * YQ * SQ;  // [B][Y][D]

  hipMemsetAsync(U, 0, (size_t)YPAD * DQ * 2, stream);

  k_prep_x<<<dim3(SQ / 64, DQ / 64, BQ), 256, 0, stream>>>(x, xb, xT);
  k_pack_w<<<dim3((KQ * DQ * EP + 255) / 256), 256, 0, stream>>>(cw, Wp);
  k_conv<<<dim3(4, (YQ + 3) / 4), 256, 0, stream>>>(c2t, embed, Wp, cb, U);
  k_scores<<<dim3(SQ / 128, (YQ + 127) / 128, BQ), 256, 0, stream>>>(
      U, xb, Pb, out_alpha, part);
  k_smfix<<<dim3((BQ * YQ + 255) / 256), 256, 0, stream>>>(part, rst,
                                                           fused ? rc : (float*)0);
  if (fused) {
    k_pv2<<<dim3(DQ / 256, (YQ + 127) / 128, BQ), 512, 0, stream>>>(
        Pb, rc, xT, fw, out_m, out_alpha, fpart);
    int nfb = (BQ * YQ + 255) / 256;   // 140
    k_final2<<<dim3(nfb), 256, 0, stream>>>(fpart, fb, target, out_y, lpart);
    k_loss_fin<<<1, 256, 0, stream>>>(lpart, nfb, out_loss);
  } else {
    k_alpha<<<dim3(BQ * YQ), 256, 0, stream>>>(out_alpha, rst);
    k_pv<<<dim3(DQ / 128, (YQ + 127) / 128, BQ), 256, 0, stream>>>(
        out_alpha, xT, out_m);
    k_final<<<dim3(YQ), 256, 0, stream>>>(out_m, fw, fb, target, out_y, lpart);
    k_loss_fin<<<1, 256, 0, stream>>>(lpart, YQ, out_loss);
  }
}